// Round 1
// baseline (396.890 us; speedup 1.0000x reference)
//
#include <hip/hip_runtime.h>
#include <math.h>

// Problem constants (B=2, L=1024, D=768, H=12, DH=64, LAT=512)
#define D_MODEL 768
#define NHEAD   12
#define LATD    512
#define BATCH   2
#define SEQ     1024
#define NROWS   (BATCH*SEQ)          // 2048
#define NCHUNK  (SEQ/64)             // 16
#define NBH     (BATCH*NHEAD)        // 24
#define QKVW    (3*D_MODEL)          // 2304

__device__ __forceinline__ float sigf(float x){ return 1.f/(1.f+expf(-x)); }
__device__ __forceinline__ float decay_of(float hd){
  float d = 0.3f + 0.65f*sigf(hd);
  return fminf(fmaxf(d, 1e-5f), 0.999f);
}

// ---------------- rmsnorm over D=768, one block per row ----------------
__global__ __launch_bounds__(256) void k_rmsnorm(const float* __restrict__ x,
    const float* __restrict__ w, float* __restrict__ y)
{
  int row = blockIdx.x, tid = threadIdx.x;
  const float* xr = x + (size_t)row*D_MODEL;
  float v0 = xr[tid], v1 = xr[tid+256], v2 = xr[tid+512];
  float s = v0*v0 + v1*v1 + v2*v2;
  #pragma unroll
  for (int off=32; off; off>>=1) s += __shfl_xor(s, off, 64);
  __shared__ float red[4];
  if ((tid & 63) == 0) red[tid>>6] = s;
  __syncthreads();
  s = red[0]+red[1]+red[2]+red[3];
  float sc = rsqrtf(s*(1.f/(float)D_MODEL) + 1e-6f);
  float* yr = y + (size_t)row*D_MODEL;
  yr[tid]     = v0*sc*w[tid];
  yr[tid+256] = v1*sc*w[tid+256];
  yr[tid+512] = v2*sc*w[tid+512];
}

// ---------------- fp32 tiled GEMM: C[M,N] = A[M,K]@B[K,N], epilogue ----------------
// act: 0 = none, 1 = silu, 2 = multiply by aux[M,N]
__global__ __launch_bounds__(256) void k_gemm(const float* __restrict__ A,
    const float* __restrict__ B, float* __restrict__ C, const float* __restrict__ aux,
    int M, int N, int K, int act)
{
  __shared__ float As[16][68];
  __shared__ float Bs[16][68];
  int bm = blockIdx.y*64, bn = blockIdx.x*64;
  int tid = threadIdx.x;
  int tx = tid & 15, ty = tid >> 4;
  int am = tid >> 2, ak = (tid & 3)*4;      // A tile: 64 rows x 16 k, float4 per thread
  int bk = tid >> 4, bn4 = (tid & 15)*4;    // B tile: 16 k x 64 cols, float4 per thread
  float acc[4][4] = {{0.f}};
  for (int kk = 0; kk < K; kk += 16){
    float4 a4 = *(const float4*)(A + (size_t)(bm+am)*K + kk + ak);
    As[ak+0][am] = a4.x; As[ak+1][am] = a4.y; As[ak+2][am] = a4.z; As[ak+3][am] = a4.w;
    float4 b4 = make_float4(0.f,0.f,0.f,0.f);
    if (bn + bn4 < N)   // N is always a multiple of 4; only N=48 needs this guard
      b4 = *(const float4*)(B + (size_t)(kk+bk)*N + bn + bn4);
    *(float4*)&Bs[bk][bn4] = b4;
    __syncthreads();
    #pragma unroll
    for (int k=0;k<16;k++){
      float4 av = *(const float4*)&As[k][ty*4];
      float4 bv = *(const float4*)&Bs[k][tx*4];
      acc[0][0] += av.x*bv.x; acc[0][1] += av.x*bv.y; acc[0][2] += av.x*bv.z; acc[0][3] += av.x*bv.w;
      acc[1][0] += av.y*bv.x; acc[1][1] += av.y*bv.y; acc[1][2] += av.y*bv.z; acc[1][3] += av.y*bv.w;
      acc[2][0] += av.z*bv.x; acc[2][1] += av.z*bv.y; acc[2][2] += av.z*bv.z; acc[2][3] += av.z*bv.w;
      acc[3][0] += av.w*bv.x; acc[3][1] += av.w*bv.y; acc[3][2] += av.w*bv.z; acc[3][3] += av.w*bv.w;
    }
    __syncthreads();
  }
  #pragma unroll
  for (int i=0;i<4;i++){
    int row = bm + ty*4 + i;
    #pragma unroll
    for (int j=0;j<4;j++){
      int col = bn + tx*4 + j;
      if (col < N){
        float c = acc[i][j];
        if (act == 1) c = c / (1.f + expf(-c));                 // silu
        else if (act == 2) c *= aux[(size_t)row*N + col];        // gated output
        C[(size_t)row*N + col] = c;
      }
    }
  }
}

// ---------------- per-(b,l) feature kernel: one wave per head ----------------
__global__ __launch_bounds__(768) void k_feat(const float* __restrict__ qkv,
    const float* __restrict__ params, const float* __restrict__ w_qn,
    const float* __restrict__ w_kn, const float* __restrict__ hdec,
    const float* __restrict__ temp, float* __restrict__ qf, float* __restrict__ kf,
    float* __restrict__ vf, float* __restrict__ cKV, float* __restrict__ cZ)
{
  int row = blockIdx.x;                 // b*1024 + t
  int h = threadIdx.x >> 6, lane = threadIdx.x & 63;
  int b = row >> 10, t = row & 1023;
  const float* qr = qkv + (size_t)row*QKVW;
  float q = qr[h*64 + lane];
  float k = qr[768 + h*64 + lane];
  float v = qr[1536 + h*64 + lane];
  // rms over DH=64 (one wave)
  float sq = q*q, sk = k*k;
  #pragma unroll
  for (int off=32; off; off>>=1){ sq += __shfl_xor(sq, off, 64); sk += __shfl_xor(sk, off, 64); }
  q = q * w_qn[lane] * rsqrtf(sq*(1.f/64.f) + 1e-6f);
  k = k * w_kn[lane] * rsqrtf(sk*(1.f/64.f) + 1e-6f);
  // rope: rotated[lane] = lane<32 ? -x[lane+32] : x[lane-32]
  float qp = __shfl_xor(q, 32, 64), kp = __shfl_xor(k, 32, 64);
  float rq = (lane < 32) ? -qp : qp;
  float rk = (lane < 32) ? -kp : kp;
  int fi = lane & 31;
  float inv = exp2f(-(float)fi*(1.f/32.f)*13.28771237954945f);   // 10000^{-2i/64}
  float ang = (float)t * inv;
  float c = cosf(ang), s = sinf(ang);
  q = q*c + rq*s;
  k = k*c + rk*s;
  // elu(x)+1
  float qfv = (q > 0.f) ? q + 1.f : expf(q);
  float kfv = (k > 0.f) ? k + 1.f : expf(k);
  size_t oidx = (((size_t)(b*NHEAD + h))*SEQ + t)*64 + lane;
  qf[oidx] = qfv; kf[oidx] = kfv; vf[oidx] = v;
  if (lane == 0){
    const float* pr = params + (size_t)row*48 + h*4;
    float sa = sigf(pr[0]);
    float sp = sigf(pr[1])*3.14159265358979323846f;
    float ca = sigf(pr[2]);
    float cp = sigf(pr[3])*3.14159265358979323846f;
    float z = sa*ca*cosf(sp - cp)*temp[0];
    float gate = fminf(fmaxf(sigf(z)*1.2f - 0.1f, 0.05f), 0.95f);
    float d = decay_of(hdec[h]);
    float df = expf((float)(t+1)*logf(d));     // matches reference's exp(cum_log)
    float g = df/(df + 1e-8f);                 // input-gate factor; ->0 when df<<1e-8
    int ci = (b*NHEAD + h)*SEQ + t;
    cKV[ci] = g*gate*(1.f - d);
    cZ[ci]  = g*(1.f - d);
  }
}

// ---------------- intra-chunk attention + per-chunk state partials ----------------
// block = (b,h,chunk); computes: num_intra[t,e], den_intra[t], P[d,e], zP[d]
__global__ __launch_bounds__(256) void k_intra(const float* __restrict__ qf,
    const float* __restrict__ kf, const float* __restrict__ vf,
    const float* __restrict__ cKVb, const float* __restrict__ cZb,
    const float* __restrict__ hdec, float* __restrict__ numb,
    float* __restrict__ denb, float* __restrict__ Pb, float* __restrict__ zPb)
{
  __shared__ float Qs[64][68], Ks[64][68], Vs[64][68];   // Qs reused as Wn after scores
  __shared__ float cn[64], cd[64], cps[64], czs[64];
  __shared__ float denp[16][64];
  int bid = blockIdx.x;
  int chunk = bid & 15, bh = bid >> 4, h = bh % NHEAD;
  size_t base = ((size_t)bh*SEQ + chunk*64)*64;
  int tid = threadIdx.x;
  #pragma unroll
  for (int i=0;i<4;i++){
    int e4 = tid + i*256;
    int r = e4 >> 4, cc = (e4 & 15)*4;
    *(float4*)&Qs[r][cc] = *(const float4*)(qf + base + r*64 + cc);
    *(float4*)&Ks[r][cc] = *(const float4*)(kf + base + r*64 + cc);
    *(float4*)&Vs[r][cc] = *(const float4*)(vf + base + r*64 + cc);
  }
  if (tid < 64){
    cn[tid] = cKVb[bh*SEQ + chunk*64 + tid];
    cd[tid] = cZb[bh*SEQ + chunk*64 + tid];
  }
  __syncthreads();
  float d = decay_of(hdec[h]);
  float l2d = log2f(d);
  int tx = tid & 15, ty = tid >> 4;
  int t0 = ty*4, s0 = tx*4;
  // scores: sc[i][j] = q_f[t0+i] . k_f[s0+j]
  float scr[4][4] = {{0.f}};
  for (int k=0;k<64;k++){
    float qv[4], kv[4];
    #pragma unroll
    for (int i=0;i<4;i++) qv[i] = Qs[t0+i][k];
    #pragma unroll
    for (int j=0;j<4;j++) kv[j] = Ks[s0+j][k];
    #pragma unroll
    for (int i=0;i<4;i++)
      #pragma unroll
      for (int j=0;j<4;j++) scr[i][j] += qv[i]*kv[j];
  }
  // causal decay weights
  float wn[4][4]; float wd[4] = {0.f,0.f,0.f,0.f};
  #pragma unroll
  for (int i=0;i<4;i++){
    #pragma unroll
    for (int j=0;j<4;j++){
      int tt = t0+i, ss = s0+j;
      float w = 0.f;
      if (ss <= tt){
        float pw = exp2f((float)(tt-ss)*l2d);    // d^{t-s}
        float sw = scr[i][j]*pw;
        w = sw*cn[ss];
        wd[i] += sw*cd[ss];
      }
      wn[i][j] = w;
    }
  }
  __syncthreads();          // everyone done reading Qs -> safe to overwrite with Wn
  #pragma unroll
  for (int i=0;i<4;i++)
    #pragma unroll
    for (int j=0;j<4;j++) Qs[t0+i][s0+j] = wn[i][j];
  #pragma unroll
  for (int i=0;i<4;i++) denp[tx][t0+i] = wd[i];
  if (tid < 64){
    float pw = exp2f((float)(63 - tid)*l2d);     // d^{chunk_end - s}
    cps[tid] = cn[tid]*pw;
    czs[tid] = cd[tid]*pw;
  }
  __syncthreads();
  // den_intra
  if (tid < 64){
    float dsum = 0.f;
    #pragma unroll
    for (int xx=0;xx<16;xx++) dsum += denp[xx][tid];
    denb[bh*SEQ + chunk*64 + tid] = dsum;
  }
  // num_intra[t,e] = sum_s Wn[t][s] * V[s][e]   (t0 rows, e0 = s0 cols)
  {
    float o[4][4] = {{0.f}};
    for (int s2=0;s2<64;s2++){
      float wv[4];
      #pragma unroll
      for (int i=0;i<4;i++) wv[i] = Qs[t0+i][s2];
      float4 vv = *(const float4*)&Vs[s2][s0];
      #pragma unroll
      for (int i=0;i<4;i++){
        o[i][0] += wv[i]*vv.x; o[i][1] += wv[i]*vv.y;
        o[i][2] += wv[i]*vv.z; o[i][3] += wv[i]*vv.w;
      }
    }
    #pragma unroll
    for (int i=0;i<4;i++)
      #pragma unroll
      for (int j=0;j<4;j++) numb[base + (size_t)(t0+i)*64 + s0+j] = o[i][j];
  }
  // P[d,e] = sum_s cps[s] * K[s][d] * V[s][e]   (d0 = t0, e0 = s0)
  {
    float p[4][4] = {{0.f}};
    for (int s2=0;s2<64;s2++){
      float cc = cps[s2];
      float4 kk4 = *(const float4*)&Ks[s2][t0];
      float4 vv = *(const float4*)&Vs[s2][s0];
      float kr0 = kk4.x*cc, kr1 = kk4.y*cc, kr2 = kk4.z*cc, kr3 = kk4.w*cc;
      p[0][0] += kr0*vv.x; p[0][1] += kr0*vv.y; p[0][2] += kr0*vv.z; p[0][3] += kr0*vv.w;
      p[1][0] += kr1*vv.x; p[1][1] += kr1*vv.y; p[1][2] += kr1*vv.z; p[1][3] += kr1*vv.w;
      p[2][0] += kr2*vv.x; p[2][1] += kr2*vv.y; p[2][2] += kr2*vv.z; p[2][3] += kr2*vv.w;
      p[3][0] += kr3*vv.x; p[3][1] += kr3*vv.y; p[3][2] += kr3*vv.z; p[3][3] += kr3*vv.w;
    }
    #pragma unroll
    for (int i=0;i<4;i++)
      #pragma unroll
      for (int j=0;j<4;j++) Pb[(size_t)bid*4096 + (t0+i)*64 + s0+j] = p[i][j];
  }
  if (tid < 64){
    float z = 0.f;
    for (int s2=0;s2<64;s2++) z += czs[s2]*Ks[s2][tid];
    zPb[bid*64 + tid] = z;
  }
}

// ---------------- chunk-level state scan: S_end[c] = d^64 * S_end[c-1] + P_c ----------------
__global__ __launch_bounds__(256) void k_scan(const float* __restrict__ Pb,
    const float* __restrict__ zPb, float* __restrict__ Sprev,
    float* __restrict__ zprev, const float* __restrict__ hdec)
{
  int bh = blockIdx.x, h = bh % NHEAD, tid = threadIdx.x;
  float d = decay_of(hdec[h]);
  float d64 = exp2f(64.f*log2f(d));
  float S[16];
  #pragma unroll
  for (int i=0;i<16;i++) S[i] = 0.f;
  float zS = 0.f;
  for (int c=0;c<NCHUNK;c++){
    size_t off = ((size_t)bh*NCHUNK + c)*4096;
    #pragma unroll
    for (int i=0;i<16;i++){
      int idx = tid + i*256;
      Sprev[off + idx] = S[i];               // state BEFORE chunk c
      S[i] = S[i]*d64 + Pb[off + idx];
    }
    if (tid < 64){
      int zoff = (bh*NCHUNK + c)*64 + tid;
      zprev[zoff] = zS;
      zS = zS*d64 + zPb[zoff];
    }
  }
}

// ---------------- cross-chunk combine + final attention output ----------------
__global__ __launch_bounds__(256) void k_cross(const float* __restrict__ qf,
    const float* __restrict__ Sprev, const float* __restrict__ zprev,
    const float* __restrict__ numb, const float* __restrict__ denb,
    const float* __restrict__ hdec, float* __restrict__ attn)
{
  __shared__ float Qs[64][68], Ss[64][68];
  __shared__ float zp[64];
  int bid = blockIdx.x;
  int chunk = bid & 15, bh = bid >> 4, h = bh % NHEAD, b = bh / NHEAD;
  size_t base = ((size_t)bh*SEQ + chunk*64)*64;
  int tid = threadIdx.x;
  #pragma unroll
  for (int i=0;i<4;i++){
    int e4 = tid + i*256;
    int r = e4 >> 4, cc = (e4 & 15)*4;
    *(float4*)&Qs[r][cc] = *(const float4*)(qf + base + r*64 + cc);
    *(float4*)&Ss[r][cc] = *(const float4*)(Sprev + (size_t)bid*4096 + r*64 + cc);
  }
  if (tid < 64) zp[tid] = zprev[bid*64 + tid];
  __syncthreads();
  float d = decay_of(hdec[h]);
  float l2d = log2f(d);
  int tx = tid & 15, ty = tid >> 4;
  int t0 = ty*4, e0 = tx*4;
  float cr[4][4] = {{0.f}};
  float dc[4] = {0.f,0.f,0.f,0.f};
  for (int k=0;k<64;k++){
    float qv[4];
    #pragma unroll
    for (int i=0;i<4;i++) qv[i] = Qs[t0+i][k];
    float4 sv = *(const float4*)&Ss[k][e0];
    float zk = zp[k];
    #pragma unroll
    for (int i=0;i<4;i++){
      dc[i] += qv[i]*zk;
      cr[i][0] += qv[i]*sv.x; cr[i][1] += qv[i]*sv.y;
      cr[i][2] += qv[i]*sv.z; cr[i][3] += qv[i]*sv.w;
    }
  }
  #pragma unroll
  for (int i=0;i<4;i++){
    int tl = t0+i;
    float pw = exp2f((float)(tl+1)*l2d);       // d^{t_local+1}: S_prev is state at c0-1
    float den = fmaxf(denb[bh*SEQ + chunk*64 + tl] + pw*dc[i], 1e-5f);
    float invden = 1.f/den;
    int tg = chunk*64 + tl;
    #pragma unroll
    for (int j=0;j<4;j++){
      float nm = numb[base + (size_t)tl*64 + e0 + j] + pw*cr[i][j];
      attn[((size_t)(b*SEQ + tg))*D_MODEL + h*64 + e0 + j] = nm*invden;
    }
  }
}

extern "C" void kernel_launch(void* const* d_in, const int* in_sizes, int n_in,
                              void* d_out, int out_size, void* d_ws, size_t ws_size,
                              hipStream_t stream)
{
  (void)in_sizes; (void)n_in; (void)out_size; (void)ws_size;
  const float* x       = (const float*)d_in[0];
  const float* w_ln    = (const float*)d_in[1];
  const float* w_comp  = (const float*)d_in[2];
  const float* w_qkv   = (const float*)d_in[3];
  const float* w_reso  = (const float*)d_in[4];
  const float* w_qn    = (const float*)d_in[5];
  const float* w_kn    = (const float*)d_in[6];
  const float* hdec    = (const float*)d_in[7];
  const float* temp    = (const float*)d_in[8];
  const float* w_ogate = (const float*)d_in[9];
  const float* w_proj  = (const float*)d_in[10];
  const float* w_mn    = (const float*)d_in[11];
  float* ws = (float*)d_ws;
  float* out = (float*)d_out;

  // workspace layout (floats); total ~18.6M floats = 74.3 MB
  const size_t o_xn     = 0;                                  // 2048*768   (reused as memn)
  const size_t o_latent = o_xn     + (size_t)NROWS*D_MODEL;   // 2048*512
  const size_t o_qkv    = o_latent + (size_t)NROWS*LATD;      // 2048*2304  (reused as num)
  const size_t o_params = o_qkv    + (size_t)NROWS*QKVW;      // 2048*48
  const size_t o_gate   = o_params + (size_t)NROWS*48;        // 2048*768
  const size_t o_q      = o_gate   + (size_t)NROWS*D_MODEL;   // 24*1024*64
  const size_t o_k      = o_q      + (size_t)NBH*SEQ*64;
  const size_t o_v      = o_k      + (size_t)NBH*SEQ*64;
  const size_t o_cKV    = o_v      + (size_t)NBH*SEQ*64;      // 24576
  const size_t o_cZ     = o_cKV    + (size_t)NBH*SEQ;
  const size_t o_den    = o_cZ     + (size_t)NBH*SEQ;
  const size_t o_P      = o_den    + (size_t)NBH*SEQ;         // 24*16*4096
  const size_t o_zP     = o_P      + (size_t)NBH*NCHUNK*4096;
  const size_t o_S      = o_zP     + (size_t)NBH*NCHUNK*64;
  const size_t o_zprev  = o_S      + (size_t)NBH*NCHUNK*4096;
  const size_t o_attn   = o_zprev  + (size_t)NBH*NCHUNK*64;

  float* num  = ws + o_qkv;   // alias: qkv dead after k_feat
  float* memn = ws + o_xn;    // alias: xn dead after first gemm

  // 1. xn = rmsnorm(x, w_ln)
  k_rmsnorm<<<NROWS, 256, 0, stream>>>(x, w_ln, ws + o_xn);
  // 2. latent = silu(xn @ w_compress)
  k_gemm<<<dim3(LATD/64, NROWS/64), 256, 0, stream>>>(ws + o_xn, w_comp, ws + o_latent, nullptr, NROWS, LATD, D_MODEL, 1);
  // 3. qkv = latent @ w_qkv
  k_gemm<<<dim3(QKVW/64, NROWS/64), 256, 0, stream>>>(ws + o_latent, w_qkv, ws + o_qkv, nullptr, NROWS, QKVW, LATD, 0);
  // 4. params = latent @ w_reso  (N=48)
  k_gemm<<<dim3(1, NROWS/64), 256, 0, stream>>>(ws + o_latent, w_reso, ws + o_params, nullptr, NROWS, 48, LATD, 0);
  // 5. gatebuf = silu(latent @ w_out_gate)
  k_gemm<<<dim3(D_MODEL/64, NROWS/64), 256, 0, stream>>>(ws + o_latent, w_ogate, ws + o_gate, nullptr, NROWS, D_MODEL, LATD, 1);
  // 6. per-head features + coefficients
  k_feat<<<NROWS, 768, 0, stream>>>(ws + o_qkv, ws + o_params, w_qn, w_kn, hdec, temp,
                                    ws + o_q, ws + o_k, ws + o_v, ws + o_cKV, ws + o_cZ);
  // 7. intra-chunk attention + chunk partials
  k_intra<<<NBH*NCHUNK, 256, 0, stream>>>(ws + o_q, ws + o_k, ws + o_v, ws + o_cKV, ws + o_cZ,
                                          hdec, num, ws + o_den, ws + o_P, ws + o_zP);
  // 8. chunk-level state scan
  k_scan<<<NBH, 256, 0, stream>>>(ws + o_P, ws + o_zP, ws + o_S, ws + o_zprev, hdec);
  // 9. cross-chunk combine -> attn (B,L,D)
  k_cross<<<NBH*NCHUNK, 256, 0, stream>>>(ws + o_q, ws + o_S, ws + o_zprev, num, ws + o_den, hdec, ws + o_attn);
  // 10. memnorm
  k_rmsnorm<<<NROWS, 256, 0, stream>>>(ws + o_attn, w_mn, memn);
  // 11. out = (memn @ w_proj) * gatebuf
  k_gemm<<<dim3(D_MODEL/64, NROWS/64), 256, 0, stream>>>(memn, w_proj, out, ws + o_gate, NROWS, D_MODEL, D_MODEL, 2);
}

// Round 2
// 286.447 us; speedup vs baseline: 1.3856x; 1.3856x over previous
//
#include <hip/hip_runtime.h>
#include <hip/hip_bf16.h>
#include <math.h>

// Problem constants (B=2, L=1024, D=768, H=12, DH=64, LAT=512)
#define D_MODEL 768
#define NHEAD   12
#define LATD    512
#define BATCH   2
#define SEQ     1024
#define NROWS   (BATCH*SEQ)          // 2048
#define NCHUNK  (SEQ/64)             // 16
#define NBH     (BATCH*NHEAD)        // 24
#define QKVW    (3*D_MODEL)          // 2304

using short8 = __attribute__((ext_vector_type(8))) short;
using f32x4  = __attribute__((ext_vector_type(4))) float;

__device__ __forceinline__ float sigf(float x){ return 1.f/(1.f+expf(-x)); }
__device__ __forceinline__ float decay_of(float hd){
  float d = 0.3f + 0.65f*sigf(hd);
  return fminf(fmaxf(d, 1e-5f), 0.999f);
}
__device__ __forceinline__ unsigned short f2b(float f){
  __hip_bfloat16 h = __float2bfloat16(f);
  return *reinterpret_cast<unsigned short*>(&h);
}
__device__ __forceinline__ void async16(const unsigned short* g, unsigned short* l){
  __builtin_amdgcn_global_load_lds((const __attribute__((address_space(1))) void*)g,
                                   (__attribute__((address_space(3))) void*)l, 16, 0, 0);
}

// ---------------- rmsnorm over D=768 -> bf16 out, one block per row ----------------
__global__ __launch_bounds__(256) void k_rmsnorm_bf(const float* __restrict__ x,
    const float* __restrict__ w, unsigned short* __restrict__ y)
{
  int row = blockIdx.x, tid = threadIdx.x;
  const float* xr = x + (size_t)row*D_MODEL;
  float v0 = xr[tid], v1 = xr[tid+256], v2 = xr[tid+512];
  float s = v0*v0 + v1*v1 + v2*v2;
  #pragma unroll
  for (int off=32; off; off>>=1) s += __shfl_xor(s, off, 64);
  __shared__ float red[4];
  if ((tid & 63) == 0) red[tid>>6] = s;
  __syncthreads();
  s = red[0]+red[1]+red[2]+red[3];
  float sc = rsqrtf(s*(1.f/(float)D_MODEL) + 1e-6f);
  unsigned short* yr = y + (size_t)row*D_MODEL;
  yr[tid]     = f2b(v0*sc*w[tid]);
  yr[tid+256] = f2b(v1*sc*w[tid+256]);
  yr[tid+512] = f2b(v2*sc*w[tid+512]);
}

// ---------------- transpose + fp32->bf16 convert: W[K][N] -> WT[N][K] ----------------
__global__ __launch_bounds__(256) void k_cvt_t(const float* __restrict__ W,
    unsigned short* __restrict__ WT, int K, int N)
{
  __shared__ unsigned short tile[64][65];
  int k0 = blockIdx.y*64, n0 = blockIdx.x*64;
  int t = threadIdx.x;
  int cr = t >> 6, cc = t & 63;
  #pragma unroll
  for (int i=0;i<16;i++){
    int r = cr + i*4;
    tile[r][cc] = f2b(W[(size_t)(k0+r)*N + n0 + cc]);
  }
  __syncthreads();
  #pragma unroll
  for (int i=0;i<16;i++){
    int nn = cr + i*4;
    WT[(size_t)(n0+nn)*K + k0 + cc] = tile[cc][nn];
  }
}

// ---------------- bf16 MFMA GEMM: C[M,N] = A[M,K] @ BT[N,K]^T ----------------
// 128x128 block tile, BK=64, 4 waves each 64x64 (4x4 16x16x32 MFMA tiles).
// act: 0 none, 1 silu, 2 multiply by aux. Cf (fp32) and/or Cb (bf16) outputs.
__global__ __launch_bounds__(256) void k_mfma_gemm(const unsigned short* __restrict__ A,
    const unsigned short* __restrict__ BT, float* __restrict__ Cf,
    unsigned short* __restrict__ Cb, const float* __restrict__ aux,
    int M, int N, int K, int act)
{
  __shared__ unsigned short As[128*64];   // 16 KB, XOR-swizzled 16B chunks
  __shared__ unsigned short Bs[128*64];
  int tid = threadIdx.x;
  int w = tid >> 6, lane = tid & 63;
  int wm = (w >> 1)*64, wn = (w & 1)*64;
  int m16 = lane & 15, quad = lane >> 4;
  int bm = blockIdx.y*128, bn = blockIdx.x*128;

  f32x4 acc[4][4];
  #pragma unroll
  for (int i=0;i<4;i++)
    #pragma unroll
    for (int j=0;j<4;j++) acc[i][j] = (f32x4){0.f,0.f,0.f,0.f};

  for (int kk = 0; kk < K; kk += 64){
    // stage A and BT tiles: 1024 16B-chunks each; chunk g -> LDS idx g,
    // holds global chunk (m = g>>3, c = (g&7) ^ (m&7))  [XOR swizzle]
    #pragma unroll
    for (int i=0;i<4;i++){
      int g = (w*4 + i)*64 + lane;
      int m = g >> 3, c = (g & 7) ^ (m & 7);
      async16(A  + (size_t)(bm+m)*K + kk + c*8, As + (w*4+i)*512);
      async16(BT + (size_t)(bn+m)*K + kk + c*8, Bs + (w*4+i)*512);
    }
    __syncthreads();
    #pragma unroll
    for (int s=0;s<2;s++){
      short8 af[4], bf[4];
      #pragma unroll
      for (int mt=0;mt<4;mt++){
        int m = wm + mt*16 + m16;
        int idx = m*8 + ((s*4 + quad) ^ (m & 7));
        af[mt] = *(const short8*)(As + idx*8);
      }
      #pragma unroll
      for (int nt=0;nt<4;nt++){
        int n = wn + nt*16 + m16;
        int idx = n*8 + ((s*4 + quad) ^ (n & 7));
        bf[nt] = *(const short8*)(Bs + idx*8);
      }
      #pragma unroll
      for (int mt=0;mt<4;mt++)
        #pragma unroll
        for (int nt=0;nt<4;nt++)
          acc[mt][nt] = __builtin_amdgcn_mfma_f32_16x16x32_bf16(af[mt], bf[nt], acc[mt][nt], 0, 0, 0);
    }
    __syncthreads();
  }
  // epilogue: D row = quad*4 + r, col = m16 within each 16x16 tile
  #pragma unroll
  for (int mt=0;mt<4;mt++){
    #pragma unroll
    for (int r=0;r<4;r++){
      int row = bm + wm + mt*16 + quad*4 + r;
      #pragma unroll
      for (int nt=0;nt<4;nt++){
        int col = bn + wn + nt*16 + m16;
        float v = acc[mt][nt][r];
        if (act == 1) v = v/(1.f + expf(-v));
        else if (act == 2) v *= aux[(size_t)row*N + col];
        if (Cf) Cf[(size_t)row*N + col] = v;
        if (Cb) Cb[(size_t)row*N + col] = f2b(v);
      }
    }
  }
}

// ---------------- fp32 tiled GEMM (kept for tiny N=48 params matmul) ----------------
__global__ __launch_bounds__(256) void k_gemm(const float* __restrict__ A,
    const float* __restrict__ B, float* __restrict__ C, const float* __restrict__ aux,
    int M, int N, int K, int act)
{
  __shared__ float As[16][68];
  __shared__ float Bs[16][68];
  int bm = blockIdx.y*64, bn = blockIdx.x*64;
  int tid = threadIdx.x;
  int tx = tid & 15, ty = tid >> 4;
  int am = tid >> 2, ak = (tid & 3)*4;
  int bk = tid >> 4, bn4 = (tid & 15)*4;
  float acc[4][4] = {{0.f}};
  for (int kk = 0; kk < K; kk += 16){
    float4 a4 = *(const float4*)(A + (size_t)(bm+am)*K + kk + ak);
    As[ak+0][am] = a4.x; As[ak+1][am] = a4.y; As[ak+2][am] = a4.z; As[ak+3][am] = a4.w;
    float4 b4 = make_float4(0.f,0.f,0.f,0.f);
    if (bn + bn4 < N)
      b4 = *(const float4*)(B + (size_t)(kk+bk)*N + bn + bn4);
    *(float4*)&Bs[bk][bn4] = b4;
    __syncthreads();
    #pragma unroll
    for (int k=0;k<16;k++){
      float4 av = *(const float4*)&As[k][ty*4];
      float4 bv = *(const float4*)&Bs[k][tx*4];
      acc[0][0] += av.x*bv.x; acc[0][1] += av.x*bv.y; acc[0][2] += av.x*bv.z; acc[0][3] += av.x*bv.w;
      acc[1][0] += av.y*bv.x; acc[1][1] += av.y*bv.y; acc[1][2] += av.y*bv.z; acc[1][3] += av.y*bv.w;
      acc[2][0] += av.z*bv.x; acc[2][1] += av.z*bv.y; acc[2][2] += av.z*bv.z; acc[2][3] += av.z*bv.w;
      acc[3][0] += av.w*bv.x; acc[3][1] += av.w*bv.y; acc[3][2] += av.w*bv.z; acc[3][3] += av.w*bv.w;
    }
    __syncthreads();
  }
  #pragma unroll
  for (int i=0;i<4;i++){
    int row = bm + ty*4 + i;
    #pragma unroll
    for (int j=0;j<4;j++){
      int col = bn + tx*4 + j;
      if (col < N){
        float c = acc[i][j];
        if (act == 1) c = c / (1.f + expf(-c));
        else if (act == 2) c *= aux[(size_t)row*N + col];
        C[(size_t)row*N + col] = c;
      }
    }
  }
}

// ---------------- per-(b,l) feature kernel: one wave per head ----------------
__global__ __launch_bounds__(768) void k_feat(const float* __restrict__ qkv,
    const float* __restrict__ params, const float* __restrict__ w_qn,
    const float* __restrict__ w_kn, const float* __restrict__ hdec,
    const float* __restrict__ temp, float* __restrict__ qf, float* __restrict__ kf,
    float* __restrict__ vf, float* __restrict__ cKV, float* __restrict__ cZ)
{
  int row = blockIdx.x;                 // b*1024 + t
  int h = threadIdx.x >> 6, lane = threadIdx.x & 63;
  int b = row >> 10, t = row & 1023;
  const float* qr = qkv + (size_t)row*QKVW;
  float q = qr[h*64 + lane];
  float k = qr[768 + h*64 + lane];
  float v = qr[1536 + h*64 + lane];
  float sq = q*q, sk = k*k;
  #pragma unroll
  for (int off=32; off; off>>=1){ sq += __shfl_xor(sq, off, 64); sk += __shfl_xor(sk, off, 64); }
  q = q * w_qn[lane] * rsqrtf(sq*(1.f/64.f) + 1e-6f);
  k = k * w_kn[lane] * rsqrtf(sk*(1.f/64.f) + 1e-6f);
  float qp = __shfl_xor(q, 32, 64), kp = __shfl_xor(k, 32, 64);
  float rq = (lane < 32) ? -qp : qp;
  float rk = (lane < 32) ? -kp : kp;
  int fi = lane & 31;
  float inv = exp2f(-(float)fi*(1.f/32.f)*13.28771237954945f);   // 10000^{-2i/64}
  float ang = (float)t * inv;
  float c = cosf(ang), s = sinf(ang);
  q = q*c + rq*s;
  k = k*c + rk*s;
  float qfv = (q > 0.f) ? q + 1.f : expf(q);
  float kfv = (k > 0.f) ? k + 1.f : expf(k);
  size_t oidx = (((size_t)(b*NHEAD + h))*SEQ + t)*64 + lane;
  qf[oidx] = qfv; kf[oidx] = kfv; vf[oidx] = v;
  if (lane == 0){
    const float* pr = params + (size_t)row*48 + h*4;
    float sa = sigf(pr[0]);
    float sp = sigf(pr[1])*3.14159265358979323846f;
    float ca = sigf(pr[2]);
    float cp = sigf(pr[3])*3.14159265358979323846f;
    float z = sa*ca*cosf(sp - cp)*temp[0];
    float gate = fminf(fmaxf(sigf(z)*1.2f - 0.1f, 0.05f), 0.95f);
    float d = decay_of(hdec[h]);
    float df = expf((float)(t+1)*logf(d));
    float g = df/(df + 1e-8f);
    int ci = (b*NHEAD + h)*SEQ + t;
    cKV[ci] = g*gate*(1.f - d);
    cZ[ci]  = g*(1.f - d);
  }
}

// ---------------- intra-chunk attention + per-chunk state partials ----------------
__global__ __launch_bounds__(256) void k_intra(const float* __restrict__ qf,
    const float* __restrict__ kf, const float* __restrict__ vf,
    const float* __restrict__ cKVb, const float* __restrict__ cZb,
    const float* __restrict__ hdec, float* __restrict__ numb,
    float* __restrict__ denb, float* __restrict__ Pb, float* __restrict__ zPb)
{
  __shared__ float Qs[64][68], Ks[64][68], Vs[64][68];
  __shared__ float cn[64], cd[64], cps[64], czs[64];
  __shared__ float denp[16][64];
  int bid = blockIdx.x;
  int chunk = bid & 15, bh = bid >> 4, h = bh % NHEAD;
  size_t base = ((size_t)bh*SEQ + chunk*64)*64;
  int tid = threadIdx.x;
  #pragma unroll
  for (int i=0;i<4;i++){
    int e4 = tid + i*256;
    int r = e4 >> 4, cc = (e4 & 15)*4;
    *(float4*)&Qs[r][cc] = *(const float4*)(qf + base + r*64 + cc);
    *(float4*)&Ks[r][cc] = *(const float4*)(kf + base + r*64 + cc);
    *(float4*)&Vs[r][cc] = *(const float4*)(vf + base + r*64 + cc);
  }
  if (tid < 64){
    cn[tid] = cKVb[bh*SEQ + chunk*64 + tid];
    cd[tid] = cZb[bh*SEQ + chunk*64 + tid];
  }
  __syncthreads();
  float d = decay_of(hdec[h]);
  float l2d = log2f(d);
  int tx = tid & 15, ty = tid >> 4;
  int t0 = ty*4, s0 = tx*4;
  float scr[4][4] = {{0.f}};
  for (int k=0;k<64;k++){
    float qv[4], kv[4];
    #pragma unroll
    for (int i=0;i<4;i++) qv[i] = Qs[t0+i][k];
    #pragma unroll
    for (int j=0;j<4;j++) kv[j] = Ks[s0+j][k];
    #pragma unroll
    for (int i=0;i<4;i++)
      #pragma unroll
      for (int j=0;j<4;j++) scr[i][j] += qv[i]*kv[j];
  }
  float wn[4][4]; float wd[4] = {0.f,0.f,0.f,0.f};
  #pragma unroll
  for (int i=0;i<4;i++){
    #pragma unroll
    for (int j=0;j<4;j++){
      int tt = t0+i, ss = s0+j;
      float w = 0.f;
      if (ss <= tt){
        float pw = exp2f((float)(tt-ss)*l2d);
        float sw = scr[i][j]*pw;
        w = sw*cn[ss];
        wd[i] += sw*cd[ss];
      }
      wn[i][j] = w;
    }
  }
  __syncthreads();
  #pragma unroll
  for (int i=0;i<4;i++)
    #pragma unroll
    for (int j=0;j<4;j++) Qs[t0+i][s0+j] = wn[i][j];
  #pragma unroll
  for (int i=0;i<4;i++) denp[tx][t0+i] = wd[i];
  if (tid < 64){
    float pw = exp2f((float)(63 - tid)*l2d);
    cps[tid] = cn[tid]*pw;
    czs[tid] = cd[tid]*pw;
  }
  __syncthreads();
  if (tid < 64){
    float dsum = 0.f;
    #pragma unroll
    for (int xx=0;xx<16;xx++) dsum += denp[xx][tid];
    denb[bh*SEQ + chunk*64 + tid] = dsum;
  }
  {
    float o[4][4] = {{0.f}};
    for (int s2=0;s2<64;s2++){
      float wv[4];
      #pragma unroll
      for (int i=0;i<4;i++) wv[i] = Qs[t0+i][s2];
      float4 vv = *(const float4*)&Vs[s2][s0];
      #pragma unroll
      for (int i=0;i<4;i++){
        o[i][0] += wv[i]*vv.x; o[i][1] += wv[i]*vv.y;
        o[i][2] += wv[i]*vv.z; o[i][3] += wv[i]*vv.w;
      }
    }
    #pragma unroll
    for (int i=0;i<4;i++)
      #pragma unroll
      for (int j=0;j<4;j++) numb[base + (size_t)(t0+i)*64 + s0+j] = o[i][j];
  }
  {
    float p[4][4] = {{0.f}};
    for (int s2=0;s2<64;s2++){
      float cc = cps[s2];
      float4 kk4 = *(const float4*)&Ks[s2][t0];
      float4 vv = *(const float4*)&Vs[s2][s0];
      float kr0 = kk4.x*cc, kr1 = kk4.y*cc, kr2 = kk4.z*cc, kr3 = kk4.w*cc;
      p[0][0] += kr0*vv.x; p[0][1] += kr0*vv.y; p[0][2] += kr0*vv.z; p[0][3] += kr0*vv.w;
      p[1][0] += kr1*vv.x; p[1][1] += kr1*vv.y; p[1][2] += kr1*vv.z; p[1][3] += kr1*vv.w;
      p[2][0] += kr2*vv.x; p[2][1] += kr2*vv.y; p[2][2] += kr2*vv.z; p[2][3] += kr2*vv.w;
      p[3][0] += kr3*vv.x; p[3][1] += kr3*vv.y; p[3][2] += kr3*vv.z; p[3][3] += kr3*vv.w;
    }
    #pragma unroll
    for (int i=0;i<4;i++)
      #pragma unroll
      for (int j=0;j<4;j++) Pb[(size_t)bid*4096 + (t0+i)*64 + s0+j] = p[i][j];
  }
  if (tid < 64){
    float z = 0.f;
    for (int s2=0;s2<64;s2++) z += czs[s2]*Ks[s2][tid];
    zPb[bid*64 + tid] = z;
  }
}

// ---------------- chunk-level state scan ----------------
__global__ __launch_bounds__(256) void k_scan(const float* __restrict__ Pb,
    const float* __restrict__ zPb, float* __restrict__ Sprev,
    float* __restrict__ zprev, const float* __restrict__ hdec)
{
  int bh = blockIdx.x, h = bh % NHEAD, tid = threadIdx.x;
  float d = decay_of(hdec[h]);
  float d64 = exp2f(64.f*log2f(d));
  float S[16];
  #pragma unroll
  for (int i=0;i<16;i++) S[i] = 0.f;
  float zS = 0.f;
  for (int c=0;c<NCHUNK;c++){
    size_t off = ((size_t)bh*NCHUNK + c)*4096;
    #pragma unroll
    for (int i=0;i<16;i++){
      int idx = tid + i*256;
      Sprev[off + idx] = S[i];
      S[i] = S[i]*d64 + Pb[off + idx];
    }
    if (tid < 64){
      int zoff = (bh*NCHUNK + c)*64 + tid;
      zprev[zoff] = zS;
      zS = zS*d64 + zPb[zoff];
    }
  }
}

// ---------------- cross-chunk combine + final attention output ----------------
__global__ __launch_bounds__(256) void k_cross(const float* __restrict__ qf,
    const float* __restrict__ Sprev, const float* __restrict__ zprev,
    const float* __restrict__ numb, const float* __restrict__ denb,
    const float* __restrict__ hdec, float* __restrict__ attn)
{
  __shared__ float Qs[64][68], Ss[64][68];
  __shared__ float zp[64];
  int bid = blockIdx.x;
  int chunk = bid & 15, bh = bid >> 4, h = bh % NHEAD, b = bh / NHEAD;
  size_t base = ((size_t)bh*SEQ + chunk*64)*64;
  int tid = threadIdx.x;
  #pragma unroll
  for (int i=0;i<4;i++){
    int e4 = tid + i*256;
    int r = e4 >> 4, cc = (e4 & 15)*4;
    *(float4*)&Qs[r][cc] = *(const float4*)(qf + base + r*64 + cc);
    *(float4*)&Ss[r][cc] = *(const float4*)(Sprev + (size_t)bid*4096 + r*64 + cc);
  }
  if (tid < 64) zp[tid] = zprev[bid*64 + tid];
  __syncthreads();
  float d = decay_of(hdec[h]);
  float l2d = log2f(d);
  int tx = tid & 15, ty = tid >> 4;
  int t0 = ty*4, e0 = tx*4;
  float cr[4][4] = {{0.f}};
  float dc[4] = {0.f,0.f,0.f,0.f};
  for (int k=0;k<64;k++){
    float qv[4];
    #pragma unroll
    for (int i=0;i<4;i++) qv[i] = Qs[t0+i][k];
    float4 sv = *(const float4*)&Ss[k][e0];
    float zk = zp[k];
    #pragma unroll
    for (int i=0;i<4;i++){
      dc[i] += qv[i]*zk;
      cr[i][0] += qv[i]*sv.x; cr[i][1] += qv[i]*sv.y;
      cr[i][2] += qv[i]*sv.z; cr[i][3] += qv[i]*sv.w;
    }
  }
  #pragma unroll
  for (int i=0;i<4;i++){
    int tl = t0+i;
    float pw = exp2f((float)(tl+1)*l2d);
    float den = fmaxf(denb[bh*SEQ + chunk*64 + tl] + pw*dc[i], 1e-5f);
    float invden = 1.f/den;
    int tg = chunk*64 + tl;
    #pragma unroll
    for (int j=0;j<4;j++){
      float nm = numb[base + (size_t)tl*64 + e0 + j] + pw*cr[i][j];
      attn[((size_t)(b*SEQ + tg))*D_MODEL + h*64 + e0 + j] = nm*invden;
    }
  }
}

extern "C" void kernel_launch(void* const* d_in, const int* in_sizes, int n_in,
                              void* d_out, int out_size, void* d_ws, size_t ws_size,
                              hipStream_t stream)
{
  (void)in_sizes; (void)n_in; (void)out_size; (void)ws_size;
  const float* x       = (const float*)d_in[0];
  const float* w_ln    = (const float*)d_in[1];
  const float* w_comp  = (const float*)d_in[2];
  const float* w_qkv   = (const float*)d_in[3];
  const float* w_reso  = (const float*)d_in[4];
  const float* w_qn    = (const float*)d_in[5];
  const float* w_kn    = (const float*)d_in[6];
  const float* hdec    = (const float*)d_in[7];
  const float* temp    = (const float*)d_in[8];
  const float* w_ogate = (const float*)d_in[9];
  const float* w_proj  = (const float*)d_in[10];
  const float* w_mn    = (const float*)d_in[11];
  float* ws = (float*)d_ws;
  float* out = (float*)d_out;

  // fp32 workspace layout (floats)
  const size_t o_xn     = 0;                                  // (free slot; kept for layout)
  const size_t o_latent = o_xn     + (size_t)NROWS*D_MODEL;   // latent fp32 (for params gemm)
  const size_t o_qkv    = o_latent + (size_t)NROWS*LATD;      // reused as num after k_feat
  const size_t o_params = o_qkv    + (size_t)NROWS*QKVW;
  const size_t o_gate   = o_params + (size_t)NROWS*48;
  const size_t o_q      = o_gate   + (size_t)NROWS*D_MODEL;
  const size_t o_k      = o_q      + (size_t)NBH*SEQ*64;
  const size_t o_v      = o_k      + (size_t)NBH*SEQ*64;
  const size_t o_cKV    = o_v      + (size_t)NBH*SEQ*64;
  const size_t o_cZ     = o_cKV    + (size_t)NBH*SEQ;
  const size_t o_den    = o_cZ     + (size_t)NBH*SEQ;
  const size_t o_P      = o_den    + (size_t)NBH*SEQ;
  const size_t o_zP     = o_P      + (size_t)NBH*NCHUNK*4096;
  const size_t o_S      = o_zP     + (size_t)NBH*NCHUNK*64;
  const size_t o_zprev  = o_S      + (size_t)NBH*NCHUNK*4096;
  const size_t o_attn   = o_zprev  + (size_t)NBH*NCHUNK*64;
  const size_t o_end    = o_attn   + (size_t)NROWS*D_MODEL;

  // bf16 workspace region (ushorts), after fp32 region
  unsigned short* bws = (unsigned short*)(ws + o_end);
  const size_t u_xn     = 0;                                  // 2048*768
  const size_t u_latent = u_xn     + (size_t)NROWS*D_MODEL;   // 2048*512
  const size_t u_memn   = u_latent + (size_t)NROWS*LATD;      // 2048*768
  const size_t u_wtc    = u_memn   + (size_t)NROWS*D_MODEL;   // 512*768
  const size_t u_wtq    = u_wtc    + (size_t)LATD*D_MODEL;    // 2304*512
  const size_t u_wtg    = u_wtq    + (size_t)QKVW*LATD;       // 768*512
  const size_t u_wtp    = u_wtg    + (size_t)D_MODEL*LATD;    // 768*768

  float* num = ws + o_qkv;   // alias: qkv dead after k_feat

  // 0. weight convert+transpose to bf16 [N][K]
  k_cvt_t<<<dim3(LATD/64,    D_MODEL/64), 256, 0, stream>>>(w_comp,  bws + u_wtc, D_MODEL, LATD);
  k_cvt_t<<<dim3(QKVW/64,    LATD/64),    256, 0, stream>>>(w_qkv,   bws + u_wtq, LATD, QKVW);
  k_cvt_t<<<dim3(D_MODEL/64, LATD/64),    256, 0, stream>>>(w_ogate, bws + u_wtg, LATD, D_MODEL);
  k_cvt_t<<<dim3(D_MODEL/64, D_MODEL/64), 256, 0, stream>>>(w_proj,  bws + u_wtp, D_MODEL, D_MODEL);
  // 1. xn = rmsnorm(x, w_ln) -> bf16
  k_rmsnorm_bf<<<NROWS, 256, 0, stream>>>(x, w_ln, bws + u_xn);
  // 2. latent = silu(xn @ w_compress) -> bf16 + fp32
  k_mfma_gemm<<<dim3(LATD/128, NROWS/128), 256, 0, stream>>>(bws + u_xn, bws + u_wtc,
      ws + o_latent, bws + u_latent, nullptr, NROWS, LATD, D_MODEL, 1);
  // 3. qkv = latent @ w_qkv -> fp32
  k_mfma_gemm<<<dim3(QKVW/128, NROWS/128), 256, 0, stream>>>(bws + u_latent, bws + u_wtq,
      ws + o_qkv, nullptr, nullptr, NROWS, QKVW, LATD, 0);
  // 4. params = latent @ w_reso (N=48, fp32 path)
  k_gemm<<<dim3(1, NROWS/64), 256, 0, stream>>>(ws + o_latent, w_reso, ws + o_params, nullptr, NROWS, 48, LATD, 0);
  // 5. gatebuf = silu(latent @ w_out_gate) -> fp32
  k_mfma_gemm<<<dim3(D_MODEL/128, NROWS/128), 256, 0, stream>>>(bws + u_latent, bws + u_wtg,
      ws + o_gate, nullptr, nullptr, NROWS, D_MODEL, LATD, 1);
  // 6. per-head features + coefficients
  k_feat<<<NROWS, 768, 0, stream>>>(ws + o_qkv, ws + o_params, w_qn, w_kn, hdec, temp,
                                    ws + o_q, ws + o_k, ws + o_v, ws + o_cKV, ws + o_cZ);
  // 7. intra-chunk attention + chunk partials
  k_intra<<<NBH*NCHUNK, 256, 0, stream>>>(ws + o_q, ws + o_k, ws + o_v, ws + o_cKV, ws + o_cZ,
                                          hdec, num, ws + o_den, ws + o_P, ws + o_zP);
  // 8. chunk-level state scan
  k_scan<<<NBH, 256, 0, stream>>>(ws + o_P, ws + o_zP, ws + o_S, ws + o_zprev, hdec);
  // 9. cross-chunk combine -> attn (B,L,D)
  k_cross<<<NBH*NCHUNK, 256, 0, stream>>>(ws + o_q, ws + o_S, ws + o_zprev, num, ws + o_den, hdec, ws + o_attn);
  // 10. memnorm -> bf16
  k_rmsnorm_bf<<<NROWS, 256, 0, stream>>>(ws + o_attn, w_mn, bws + u_memn);
  // 11. out = (memn @ w_proj) * gatebuf
  k_mfma_gemm<<<dim3(D_MODEL/128, NROWS/128), 256, 0, stream>>>(bws + u_memn, bws + u_wtp,
      out, nullptr, ws + o_gate, NROWS, D_MODEL, D_MODEL, 2);
}

// Round 3
// 231.939 us; speedup vs baseline: 1.7112x; 1.2350x over previous
//
#include <hip/hip_runtime.h>
#include <hip/hip_bf16.h>
#include <math.h>

// Problem constants (B=2, L=1024, D=768, H=12, DH=64, LAT=512)
#define D_MODEL 768
#define NHEAD   12
#define LATD    512
#define BATCH   2
#define SEQ     1024
#define NROWS   (BATCH*SEQ)          // 2048
#define NCHUNK  (SEQ/64)             // 16
#define NBH     (BATCH*NHEAD)        // 24
#define QKVW    (3*D_MODEL)          // 2304
#define QKV2    2432                 // qkv (2304) + reso (48) padded to 19*128
#define PQ      72                   // LDS ushort pitch (144 B rows, 16B-aligned frags)

using short8 = __attribute__((ext_vector_type(8))) short;
using f32x4  = __attribute__((ext_vector_type(4))) float;

__device__ __forceinline__ float sigf(float x){ return 1.f/(1.f+expf(-x)); }
__device__ __forceinline__ float decay_of(float hd){
  float d = 0.3f + 0.65f*sigf(hd);
  return fminf(fmaxf(d, 1e-5f), 0.999f);
}
__device__ __forceinline__ unsigned short f2b(float f){
  __hip_bfloat16 h = __float2bfloat16(f);
  return *reinterpret_cast<unsigned short*>(&h);
}
__device__ __forceinline__ float bf2f(unsigned short u){
  unsigned int x = ((unsigned int)u) << 16;
  return __uint_as_float(x);
}
__device__ __forceinline__ void async16(const unsigned short* g, unsigned short* l){
  __builtin_amdgcn_global_load_lds((const __attribute__((address_space(1))) void*)g,
                                   (__attribute__((address_space(3))) void*)l, 16, 0, 0);
}

// ---------------- rmsnorm over D=768 -> bf16 out, one block per row ----------------
__global__ __launch_bounds__(256) void k_rmsnorm_bf(const float* __restrict__ x,
    const float* __restrict__ w, unsigned short* __restrict__ y)
{
  int row = blockIdx.x, tid = threadIdx.x;
  const float* xr = x + (size_t)row*D_MODEL;
  float v0 = xr[tid], v1 = xr[tid+256], v2 = xr[tid+512];
  float s = v0*v0 + v1*v1 + v2*v2;
  #pragma unroll
  for (int off=32; off; off>>=1) s += __shfl_xor(s, off, 64);
  __shared__ float red[4];
  if ((tid & 63) == 0) red[tid>>6] = s;
  __syncthreads();
  s = red[0]+red[1]+red[2]+red[3];
  float sc = rsqrtf(s*(1.f/(float)D_MODEL) + 1e-6f);
  unsigned short* yr = y + (size_t)row*D_MODEL;
  yr[tid]     = f2b(v0*sc*w[tid]);
  yr[tid+256] = f2b(v1*sc*w[tid+256]);
  yr[tid+512] = f2b(v2*sc*w[tid+512]);
}

// ---------------- transpose + fp32->bf16 convert: W[K][N] -> WT[N][K] ----------------
__global__ __launch_bounds__(256) void k_cvt_t(const float* __restrict__ W,
    unsigned short* __restrict__ WT, int K, int N)
{
  __shared__ unsigned short tile[64][65];
  int k0 = blockIdx.y*64, n0 = blockIdx.x*64;
  int t = threadIdx.x;
  int cr = t >> 6, cc = t & 63;
  #pragma unroll
  for (int i=0;i<16;i++){
    int r = cr + i*4;
    tile[r][cc] = f2b(W[(size_t)(k0+r)*N + n0 + cc]);
  }
  __syncthreads();
  #pragma unroll
  for (int i=0;i<16;i++){
    int nn = cr + i*4;
    WT[(size_t)(n0+nn)*K + k0 + cc] = tile[cc][nn];
  }
}

// ---------------- w_reso [512][48] -> WT rows 2304..2431 (pad to 2432) ----------------
__global__ __launch_bounds__(256) void k_cvt_reso(const float* __restrict__ W,
    unsigned short* __restrict__ WT)
{
  int e = blockIdx.x*256 + threadIdx.x;    // 0..65535 over 128 rows x 512 k
  int n = 2304 + (e >> 9);
  int k = e & 511;
  float v = (n < 2352) ? W[(size_t)k*48 + (n-2304)] : 0.f;
  WT[(size_t)n*512 + k] = f2b(v);
}

// ---------------- bf16 MFMA GEMM: C[M,N] = A[M,K] @ BT[N,K]^T ----------------
__global__ __launch_bounds__(256) void k_mfma_gemm(const unsigned short* __restrict__ A,
    const unsigned short* __restrict__ BT, float* __restrict__ Cf,
    unsigned short* __restrict__ Cb, const float* __restrict__ aux,
    int M, int N, int K, int act)
{
  __shared__ unsigned short As[128*64];
  __shared__ unsigned short Bs[128*64];
  int tid = threadIdx.x;
  int w = tid >> 6, lane = tid & 63;
  int wm = (w >> 1)*64, wn = (w & 1)*64;
  int m16 = lane & 15, quad = lane >> 4;
  int bm = blockIdx.y*128, bn = blockIdx.x*128;

  f32x4 acc[4][4];
  #pragma unroll
  for (int i=0;i<4;i++)
    #pragma unroll
    for (int j=0;j<4;j++) acc[i][j] = (f32x4){0.f,0.f,0.f,0.f};

  for (int kk = 0; kk < K; kk += 64){
    #pragma unroll
    for (int i=0;i<4;i++){
      int g = (w*4 + i)*64 + lane;
      int m = g >> 3, c = (g & 7) ^ (m & 7);
      async16(A  + (size_t)(bm+m)*K + kk + c*8, As + (w*4+i)*512);
      async16(BT + (size_t)(bn+m)*K + kk + c*8, Bs + (w*4+i)*512);
    }
    __syncthreads();
    #pragma unroll
    for (int s=0;s<2;s++){
      short8 af[4], bf[4];
      #pragma unroll
      for (int mt=0;mt<4;mt++){
        int m = wm + mt*16 + m16;
        int idx = m*8 + ((s*4 + quad) ^ (m & 7));
        af[mt] = *(const short8*)(As + idx*8);
      }
      #pragma unroll
      for (int nt=0;nt<4;nt++){
        int n = wn + nt*16 + m16;
        int idx = n*8 + ((s*4 + quad) ^ (n & 7));
        bf[nt] = *(const short8*)(Bs + idx*8);
      }
      #pragma unroll
      for (int mt=0;mt<4;mt++)
        #pragma unroll
        for (int nt=0;nt<4;nt++)
          acc[mt][nt] = __builtin_amdgcn_mfma_f32_16x16x32_bf16(af[mt], bf[nt], acc[mt][nt], 0, 0, 0);
    }
    __syncthreads();
  }
  #pragma unroll
  for (int mt=0;mt<4;mt++){
    #pragma unroll
    for (int r=0;r<4;r++){
      int row = bm + wm + mt*16 + quad*4 + r;
      #pragma unroll
      for (int nt=0;nt<4;nt++){
        int col = bn + wn + nt*16 + m16;
        float v = acc[mt][nt][r];
        if (act == 1) v = v/(1.f + expf(-v));
        else if (act == 2) v *= aux[(size_t)row*N + col];
        if (Cf) Cf[(size_t)row*N + col] = v;
        if (Cb) Cb[(size_t)row*N + col] = f2b(v);
      }
    }
  }
}

// ---------------- per-(b,l) feature kernel: one wave per head, bf16 outputs ----------------
__global__ __launch_bounds__(768) void k_feat(const float* __restrict__ qkv,
    const float* __restrict__ w_qn, const float* __restrict__ w_kn,
    const float* __restrict__ hdec, const float* __restrict__ temp,
    unsigned short* __restrict__ qf, unsigned short* __restrict__ kf,
    unsigned short* __restrict__ vf, float* __restrict__ cKV,
    float* __restrict__ cZ, float* __restrict__ cG)
{
  int row = blockIdx.x;                 // b*1024 + t
  int h = threadIdx.x >> 6, lane = threadIdx.x & 63;
  int b = row >> 10, t = row & 1023;
  const float* qr = qkv + (size_t)row*QKV2;
  float q = qr[h*64 + lane];
  float k = qr[768 + h*64 + lane];
  float v = qr[1536 + h*64 + lane];
  float sq = q*q, sk = k*k;
  #pragma unroll
  for (int off=32; off; off>>=1){ sq += __shfl_xor(sq, off, 64); sk += __shfl_xor(sk, off, 64); }
  q = q * w_qn[lane] * rsqrtf(sq*(1.f/64.f) + 1e-6f);
  k = k * w_kn[lane] * rsqrtf(sk*(1.f/64.f) + 1e-6f);
  float qp = __shfl_xor(q, 32, 64), kp = __shfl_xor(k, 32, 64);
  float rq = (lane < 32) ? -qp : qp;
  float rk = (lane < 32) ? -kp : kp;
  int fi = lane & 31;
  float inv = exp2f(-(float)fi*(1.f/32.f)*13.28771237954945f);   // 10000^{-2i/64}
  float ang = (float)t * inv;
  float c = cosf(ang), s = sinf(ang);
  q = q*c + rq*s;
  k = k*c + rk*s;
  float qfv = (q > 0.f) ? q + 1.f : expf(q);
  float kfv = (k > 0.f) ? k + 1.f : expf(k);
  size_t oidx = (((size_t)(b*NHEAD + h))*SEQ + t)*64 + lane;
  qf[oidx] = f2b(qfv); kf[oidx] = f2b(kfv); vf[oidx] = f2b(v);
  if (lane == 0){
    const float* pr = qr + 2304 + h*4;
    float sa = sigf(pr[0]);
    float sp = sigf(pr[1])*3.14159265358979323846f;
    float ca = sigf(pr[2]);
    float cp = sigf(pr[3])*3.14159265358979323846f;
    float z = sa*ca*cosf(sp - cp)*temp[0];
    float gate = fminf(fmaxf(sigf(z)*1.2f - 0.1f, 0.05f), 0.95f);
    float d = decay_of(hdec[h]);
    float df = expf((float)(t+1)*logf(d));
    float g = df/(df + 1e-8f);
    int ci = (b*NHEAD + h)*SEQ + t;
    cKV[ci] = g*gate*(1.f - d);
    cZ[ci]  = g*(1.f - d);
    cG[ci]  = 1.f/gate;
  }
}

// ---------------- intra-chunk: MFMA scores + num/den + P^T/zP ----------------
// block = (bh, chunk), 256 threads = 4 waves; wave w owns t-tile (and d-tile) w.
__global__ __launch_bounds__(256) void k_intra(const unsigned short* __restrict__ qf,
    const unsigned short* __restrict__ kf, const unsigned short* __restrict__ vf,
    const float* __restrict__ cKVb, const float* __restrict__ cZb,
    const float* __restrict__ cGb, const float* __restrict__ hdec,
    float* __restrict__ numb, float* __restrict__ denb,
    float* __restrict__ Pb, float* __restrict__ zPb)
{
  __shared__ __align__(16) unsigned short Qb[64*PQ];   // Q_f  [t][k]
  __shared__ __align__(16) unsigned short Kb[64*PQ];   // K_f  [s][d]
  __shared__ __align__(16) unsigned short KtS[64*PQ];  // (K_f*cps)^T [d][s]
  __shared__ __align__(16) unsigned short Wb[64*PQ];   // Wn   [t][s]
  __shared__ __align__(16) unsigned short Vt[80*PQ];   // V^T  [e][s]; row64 = invgate; 65..79 = 0
  __shared__ float cn[64], cps[64];
  int bid = blockIdx.x;
  int chunk = bid & 15, bh = bid >> 4, h = bh % NHEAD;
  int tid = threadIdx.x, w = tid >> 6, lane = tid & 63;
  int m16 = lane & 15, quad = lane >> 4;
  size_t base = ((size_t)bh*SEQ + chunk*64)*64;
  float d = decay_of(hdec[h]);
  float l2d = log2f(d);

  if (tid < 64){
    float c = cKVb[bh*SEQ + chunk*64 + tid];
    float pw = exp2f((float)(63 - tid)*l2d);
    cn[tid] = c;
    cps[tid] = c*pw;
    (void)cZb;
    Vt[64*PQ + tid] = f2b(cGb[bh*SEQ + chunk*64 + tid]);
  }
  for (int i = tid; i < 15*PQ; i += 256) Vt[65*PQ + i] = 0;
  __syncthreads();   // cps ready for KtS staging

  // stage Qb, Kb natural (contiguous 16B)
  #pragma unroll
  for (int i=0;i<2;i++){
    int g = tid + i*256;
    int r = g >> 3, c8 = (g & 7)*8;
    *(short8*)(Qb + r*PQ + c8) = *(const short8*)(qf + base + r*64 + c8);
    *(short8*)(Kb + r*PQ + c8) = *(const short8*)(kf + base + r*64 + c8);
  }
  // stage Vt, KtS transposed: thread owns column s = tid&63 (conflict-free LDS writes)
  {
    int s = tid & 63;
    float cpss = cps[s];
    #pragma unroll
    for (int i=0;i<2;i++){
      int c8 = ((tid >> 6) + i*4)*8;
      short8 vv = *(const short8*)(vf + base + s*64 + c8);
      short8 kk = *(const short8*)(kf + base + s*64 + c8);
      #pragma unroll
      for (int j=0;j<8;j++){
        Vt[(c8+j)*PQ + s] = ((unsigned short*)&vv)[j];
        KtS[(c8+j)*PQ + s] = f2b(bf2f(((unsigned short*)&kk)[j])*cpss);
      }
    }
  }
  __syncthreads();

  // -------- scores -> decay weights -> Wb (wave w: t-tile w) --------
  int trow = w*16 + quad*4;
  for (int stile=0; stile<4; stile++){
    if (stile > w){
      #pragma unroll
      for (int r=0;r<4;r++) Wb[(trow+r)*PQ + stile*16 + m16] = 0;
      continue;
    }
    f32x4 acc = (f32x4){0.f,0.f,0.f,0.f};
    #pragma unroll
    for (int ks=0;ks<2;ks++){
      short8 a = *(const short8*)(Qb + (w*16 + m16)*PQ + ks*32 + quad*8);
      short8 b = *(const short8*)(Kb + (stile*16 + m16)*PQ + ks*32 + quad*8);
      acc = __builtin_amdgcn_mfma_f32_16x16x32_bf16(a, b, acc, 0, 0, 0);
    }
    int s = stile*16 + m16;
    float cns = cn[s];
    #pragma unroll
    for (int r=0;r<4;r++){
      int t = trow + r;
      float wv = 0.f;
      if (s <= t) wv = acc[r]*exp2f((float)(t-s)*l2d)*cns;
      Wb[t*PQ + s] = f2b(wv);
    }
  }
  __syncthreads();

  // -------- num[t][e] (+den col 64) = Wn @ Vt^T --------
  {
    f32x4 acc[5];
    #pragma unroll
    for (int et=0;et<5;et++) acc[et] = (f32x4){0.f,0.f,0.f,0.f};
    #pragma unroll
    for (int et=0;et<5;et++)
      #pragma unroll
      for (int ks=0;ks<2;ks++){
        short8 a = *(const short8*)(Wb + (w*16 + m16)*PQ + ks*32 + quad*8);
        short8 b = *(const short8*)(Vt + (et*16 + m16)*PQ + ks*32 + quad*8);
        acc[et] = __builtin_amdgcn_mfma_f32_16x16x32_bf16(a, b, acc[et], 0, 0, 0);
      }
    #pragma unroll
    for (int et=0;et<4;et++)
      #pragma unroll
      for (int r=0;r<4;r++)
        numb[base + (size_t)(trow+r)*64 + et*16 + m16] = acc[et][r];
    if (m16 == 0){
      #pragma unroll
      for (int r=0;r<4;r++)
        denb[bh*SEQ + chunk*64 + trow + r] = acc[4][r];
    }
  }
  // -------- P^T[e][d] (+zP row 64) = Vt @ KtS^T; 20 tiles strided over waves --------
  {
    #pragma unroll
    for (int j=0;j<5;j++){
      int tIdx = w + 4*j;
      int et = tIdx >> 2, dt = tIdx & 3;
      f32x4 acc = (f32x4){0.f,0.f,0.f,0.f};
      #pragma unroll
      for (int ks=0;ks<2;ks++){
        short8 a = *(const short8*)(Vt  + (et*16 + m16)*PQ + ks*32 + quad*8);
        short8 b = *(const short8*)(KtS + (dt*16 + m16)*PQ + ks*32 + quad*8);
        acc = __builtin_amdgcn_mfma_f32_16x16x32_bf16(a, b, acc, 0, 0, 0);
      }
      if (et < 4){
        #pragma unroll
        for (int r=0;r<4;r++)
          Pb[(size_t)bid*4096 + (et*16 + quad*4 + r)*64 + dt*16 + m16] = acc[r];
      } else {
        if (quad == 0) zPb[bid*64 + dt*16 + m16] = acc[0];   // row e==64 only
      }
    }
  }
}

// ---------------- chunk-level state scan (parallel): S layout [e][d] ----------------
__global__ __launch_bounds__(256) void k_scan(const float* __restrict__ Pb,
    const float* __restrict__ zPb, float* __restrict__ Sprev,
    float* __restrict__ zprev, const float* __restrict__ hdec)
{
  int bh = blockIdx.x >> 2, part = blockIdx.x & 3;
  int h = bh % NHEAD, tid = threadIdx.x;
  float d = decay_of(hdec[h]);
  float d64 = exp2f(64.f*log2f(d));
  int idx = part*1024 + tid*4;
  float4 S = make_float4(0.f,0.f,0.f,0.f);
  for (int c=0;c<NCHUNK;c++){
    size_t off = ((size_t)bh*NCHUNK + c)*4096 + idx;
    *(float4*)(Sprev + off) = S;
    float4 p = *(const float4*)(Pb + off);
    S.x = S.x*d64 + p.x; S.y = S.y*d64 + p.y;
    S.z = S.z*d64 + p.z; S.w = S.w*d64 + p.w;
  }
  if (part == 0 && tid < 64){
    float z = 0.f;
    for (int c=0;c<NCHUNK;c++){
      int zoff = (bh*NCHUNK + c)*64 + tid;
      zprev[zoff] = z;
      z = z*d64 + zPb[zoff];
    }
  }
}

// ---------------- cross-chunk combine via MFMA + final attention out ----------------
__global__ __launch_bounds__(256) void k_cross(const unsigned short* __restrict__ qf,
    const float* __restrict__ Sprev, const float* __restrict__ zprev,
    const float* __restrict__ numb, const float* __restrict__ denb,
    const float* __restrict__ hdec, float* __restrict__ attn)
{
  __shared__ __align__(16) unsigned short Qb[64*PQ];   // Q_f [t][k]
  __shared__ __align__(16) unsigned short Sp[80*PQ];   // S^T-ish [e][k=d]; row64 = zprev
  __shared__ float den_sm[64];
  int bid = blockIdx.x;
  int chunk = bid & 15, bh = bid >> 4, h = bh % NHEAD, b = bh / NHEAD;
  int tid = threadIdx.x, w = tid >> 6, lane = tid & 63;
  int m16 = lane & 15, quad = lane >> 4;
  size_t base = ((size_t)bh*SEQ + chunk*64)*64;
  float d = decay_of(hdec[h]);
  float l2d = log2f(d);

  #pragma unroll
  for (int i=0;i<2;i++){
    int g = tid + i*256;
    int r = g >> 3, c8 = (g & 7)*8;
    *(short8*)(Qb + r*PQ + c8) = *(const short8*)(qf + base + r*64 + c8);
  }
  #pragma unroll
  for (int i=0;i<4;i++){
    int g = tid + i*256;               // 1024 float4 chunks of Sprev [e][d]
    int r = g >> 4, c4 = (g & 15)*4;
    float4 sv = *(const float4*)(Sprev + (size_t)bid*4096 + r*64 + c4);
    unsigned short* p = Sp + r*PQ + c4;
    p[0] = f2b(sv.x); p[1] = f2b(sv.y); p[2] = f2b(sv.z); p[3] = f2b(sv.w);
  }
  if (tid < 64) Sp[64*PQ + tid] = f2b(zprev[bid*64 + tid]);
  for (int i = tid; i < 15*PQ; i += 256) Sp[65*PQ + i] = 0;
  __syncthreads();

  f32x4 acc[5];
  #pragma unroll
  for (int et=0;et<5;et++) acc[et] = (f32x4){0.f,0.f,0.f,0.f};
  #pragma unroll
  for (int et=0;et<5;et++)
    #pragma unroll
    for (int ks=0;ks<2;ks++){
      short8 a = *(const short8*)(Qb + (w*16 + m16)*PQ + ks*32 + quad*8);
      short8 b = *(const short8*)(Sp + (et*16 + m16)*PQ + ks*32 + quad*8);
      acc[et] = __builtin_amdgcn_mfma_f32_16x16x32_bf16(a, b, acc[et], 0, 0, 0);
    }
  int trow = w*16 + quad*4;
  if (m16 == 0){
    #pragma unroll
    for (int r=0;r<4;r++){
      int tl = trow + r;
      float pw = exp2f((float)(tl+1)*l2d);
      float den = fmaxf(denb[bh*SEQ + chunk*64 + tl] + pw*acc[4][r], 1e-5f);
      den_sm[tl] = 1.f/den;
    }
  }
  __syncthreads();
  #pragma unroll
  for (int r=0;r<4;r++){
    int tl = trow + r;
    float pw = exp2f((float)(tl+1)*l2d);
    float invden = den_sm[tl];
    int tg = chunk*64 + tl;
    #pragma unroll
    for (int et=0;et<4;et++){
      int e = et*16 + m16;
      float nm = numb[base + (size_t)tl*64 + e] + pw*acc[et][r];
      attn[((size_t)(b*SEQ + tg))*D_MODEL + h*64 + e] = nm*invden;
    }
  }
}

extern "C" void kernel_launch(void* const* d_in, const int* in_sizes, int n_in,
                              void* d_out, int out_size, void* d_ws, size_t ws_size,
                              hipStream_t stream)
{
  (void)in_sizes; (void)n_in; (void)out_size; (void)ws_size;
  const float* x       = (const float*)d_in[0];
  const float* w_ln    = (const float*)d_in[1];
  const float* w_comp  = (const float*)d_in[2];
  const float* w_qkv   = (const float*)d_in[3];
  const float* w_reso  = (const float*)d_in[4];
  const float* w_qn    = (const float*)d_in[5];
  const float* w_kn    = (const float*)d_in[6];
  const float* hdec    = (const float*)d_in[7];
  const float* temp    = (const float*)d_in[8];
  const float* w_ogate = (const float*)d_in[9];
  const float* w_proj  = (const float*)d_in[10];
  const float* w_mn    = (const float*)d_in[11];
  float* ws = (float*)d_ws;
  float* out = (float*)d_out;

  // fp32 region (floats)
  const size_t o_qkv   = 0;                                   // 2048*2432 (reused as numb)
  const size_t o_gate  = o_qkv   + (size_t)NROWS*QKV2;        // 2048*768
  const size_t o_cKV   = o_gate  + (size_t)NROWS*D_MODEL;
  const size_t o_cZ    = o_cKV   + (size_t)NBH*SEQ;
  const size_t o_cG    = o_cZ    + (size_t)NBH*SEQ;
  const size_t o_den   = o_cG    + (size_t)NBH*SEQ;
  const size_t o_P     = o_den   + (size_t)NBH*SEQ;           // 24*16*4096 ([e][d] layout)
  const size_t o_zP    = o_P     + (size_t)NBH*NCHUNK*4096;
  const size_t o_S     = o_zP    + (size_t)NBH*NCHUNK*64;
  const size_t o_zprev = o_S     + (size_t)NBH*NCHUNK*4096;
  const size_t o_attn  = o_zprev + (size_t)NBH*NCHUNK*64;
  const size_t o_end   = o_attn  + (size_t)NROWS*D_MODEL;

  // bf16 region (ushorts)
  unsigned short* bws = (unsigned short*)(ws + o_end);
  const size_t u_xn     = 0;
  const size_t u_latent = u_xn     + (size_t)NROWS*D_MODEL;
  const size_t u_memn   = u_latent + (size_t)NROWS*LATD;
  const size_t u_q      = u_memn   + (size_t)NROWS*D_MODEL;
  const size_t u_k      = u_q      + (size_t)NBH*SEQ*64;
  const size_t u_v      = u_k      + (size_t)NBH*SEQ*64;
  const size_t u_wtc    = u_v      + (size_t)NBH*SEQ*64;
  const size_t u_wtq    = u_wtc    + (size_t)LATD*D_MODEL;    // 2432*512
  const size_t u_wtg    = u_wtq    + (size_t)QKV2*LATD;
  const size_t u_wtp    = u_wtg    + (size_t)D_MODEL*LATD;

  float* numb = ws + o_qkv;   // alias: qkv dead after k_feat

  // 0. weight convert+transpose to bf16 [N][K]
  k_cvt_t<<<dim3(LATD/64,    D_MODEL/64), 256, 0, stream>>>(w_comp,  bws + u_wtc, D_MODEL, LATD);
  k_cvt_t<<<dim3(QKVW/64,    LATD/64),    256, 0, stream>>>(w_qkv,   bws + u_wtq, LATD, QKVW);
  k_cvt_reso<<<256, 256, 0, stream>>>(w_reso, bws + u_wtq);
  k_cvt_t<<<dim3(D_MODEL/64, LATD/64),    256, 0, stream>>>(w_ogate, bws + u_wtg, LATD, D_MODEL);
  k_cvt_t<<<dim3(D_MODEL/64, D_MODEL/64), 256, 0, stream>>>(w_proj,  bws + u_wtp, D_MODEL, D_MODEL);
  // 1. xn = rmsnorm(x, w_ln) -> bf16
  k_rmsnorm_bf<<<NROWS, 256, 0, stream>>>(x, w_ln, bws + u_xn);
  // 2. latent = silu(xn @ w_compress) -> bf16
  k_mfma_gemm<<<dim3(LATD/128, NROWS/128), 256, 0, stream>>>(bws + u_xn, bws + u_wtc,
      nullptr, bws + u_latent, nullptr, NROWS, LATD, D_MODEL, 1);
  // 3. qkv+params = latent @ [w_qkv | w_reso | 0]  (N=2432) -> fp32
  k_mfma_gemm<<<dim3(QKV2/128, NROWS/128), 256, 0, stream>>>(bws + u_latent, bws + u_wtq,
      ws + o_qkv, nullptr, nullptr, NROWS, QKV2, LATD, 0);
  // 4. gatebuf = silu(latent @ w_out_gate) -> fp32
  k_mfma_gemm<<<dim3(D_MODEL/128, NROWS/128), 256, 0, stream>>>(bws + u_latent, bws + u_wtg,
      ws + o_gate, nullptr, nullptr, NROWS, D_MODEL, LATD, 1);
  // 5. per-head features + coefficients (bf16 q/k/v)
  k_feat<<<NROWS, 768, 0, stream>>>(ws + o_qkv, w_qn, w_kn, hdec, temp,
      bws + u_q, bws + u_k, bws + u_v, ws + o_cKV, ws + o_cZ, ws + o_cG);
  // 6. intra-chunk (MFMA)
  k_intra<<<NBH*NCHUNK, 256, 0, stream>>>(bws + u_q, bws + u_k, bws + u_v,
      ws + o_cKV, ws + o_cZ, ws + o_cG, hdec, numb, ws + o_den, ws + o_P, ws + o_zP);
  // 7. chunk-level scan (parallel)
  k_scan<<<NBH*4, 256, 0, stream>>>(ws + o_P, ws + o_zP, ws + o_S, ws + o_zprev, hdec);
  // 8. cross-chunk combine (MFMA) -> attn
  k_cross<<<NBH*NCHUNK, 256, 0, stream>>>(bws + u_q, ws + o_S, ws + o_zprev,
      numb, ws + o_den, hdec, ws + o_attn);
  // 9. memnorm -> bf16
  k_rmsnorm_bf<<<NROWS, 256, 0, stream>>>(ws + o_attn, w_mn, bws + u_memn);
  // 10. out = (memn @ w_proj) * gatebuf
  k_mfma_gemm<<<dim3(D_MODEL/128, NROWS/128), 256, 0, stream>>>(bws + u_memn, bws + u_wtp,
      out, nullptr, ws + o_gate, NROWS, D_MODEL, D_MODEL, 2);
}

// Round 4
// 182.728 us; speedup vs baseline: 2.1720x; 1.2693x over previous
//
#include <hip/hip_runtime.h>
#include <hip/hip_bf16.h>
#include <math.h>

// Problem constants (B=2, L=1024, D=768, H=12, DH=64, LAT=512)
#define D_MODEL 768
#define NHEAD   12
#define LATD    512
#define BATCH   2
#define SEQ     1024
#define NROWS   (BATCH*SEQ)          // 2048
#define NCHUNK  (SEQ/64)             // 16
#define NBH     (BATCH*NHEAD)        // 24
#define NFUSE   3200                 // qkv 2304 + params pad 128 + gate 768
#define PQ      72                   // LDS ushort pitch (144 B rows, 16B-aligned frags)

using short8 = __attribute__((ext_vector_type(8))) short;
using f32x4  = __attribute__((ext_vector_type(4))) float;

__device__ __forceinline__ float sigf(float x){ return 1.f/(1.f+expf(-x)); }
__device__ __forceinline__ float decay_of(float hd){
  float d = 0.3f + 0.65f*sigf(hd);
  return fminf(fmaxf(d, 1e-5f), 0.999f);
}
__device__ __forceinline__ unsigned short f2b(float f){
  __hip_bfloat16 h = __float2bfloat16(f);
  return *reinterpret_cast<unsigned short*>(&h);
}
__device__ __forceinline__ float bf2f(unsigned short u){
  unsigned int x = ((unsigned int)u) << 16;
  return __uint_as_float(x);
}
__device__ __forceinline__ void async16(const unsigned short* g, unsigned short* l){
  __builtin_amdgcn_global_load_lds((const __attribute__((address_space(1))) void*)g,
                                   (__attribute__((address_space(3))) void*)l, 16, 0, 0);
}

// ---------------- rmsnorm over D=768 -> bf16 out, one block per row ----------------
__global__ __launch_bounds__(256) void k_rmsnorm_bf(const float* __restrict__ x,
    const float* __restrict__ w, unsigned short* __restrict__ y)
{
  int row = blockIdx.x, tid = threadIdx.x;
  const float* xr = x + (size_t)row*D_MODEL;
  float v0 = xr[tid], v1 = xr[tid+256], v2 = xr[tid+512];
  float s = v0*v0 + v1*v1 + v2*v2;
  #pragma unroll
  for (int off=32; off; off>>=1) s += __shfl_xor(s, off, 64);
  __shared__ float red[4];
  if ((tid & 63) == 0) red[tid>>6] = s;
  __syncthreads();
  s = red[0]+red[1]+red[2]+red[3];
  float sc = rsqrtf(s*(1.f/(float)D_MODEL) + 1e-6f);
  unsigned short* yr = y + (size_t)row*D_MODEL;
  yr[tid]     = f2b(v0*sc*w[tid]);
  yr[tid+256] = f2b(v1*sc*w[tid+256]);
  yr[tid+512] = f2b(v2*sc*w[tid+512]);
}

// ---------------- ALL weight converts/transposes in one launch (640 blocks) --------
__global__ __launch_bounds__(256) void k_cvt_all(const float* __restrict__ wc,
    const float* __restrict__ wq, const float* __restrict__ wr,
    const float* __restrict__ wg, const float* __restrict__ wp,
    unsigned short* __restrict__ wtc, unsigned short* __restrict__ wtq,
    unsigned short* __restrict__ wtg, unsigned short* __restrict__ wtp)
{
  __shared__ unsigned short tile[64][65];
  int blk = blockIdx.x, t = threadIdx.x;
  const float* W; unsigned short* WT; int K, N, bx, by;
  if (blk < 96){ W=wc; WT=wtc; K=768; N=512; bx=blk&7; by=blk>>3; }
  else if (blk < 384){ int i=blk-96;  W=wq; WT=wtq; K=512; N=2304; bx=i%36; by=i/36; }
  else if (blk < 480){ int i=blk-384; W=wg; WT=wtg; K=512; N=768;  bx=i%12; by=i/12; }
  else if (blk < 624){ int i=blk-480; W=wp; WT=wtp; K=768; N=768;  bx=i%12; by=i/12; }
  else {
    // w_reso [512][48] -> wtq rows 2304..2431 (zero-pad 2352..2431)
    int i = blk - 624;                    // 0..15
    #pragma unroll
    for (int j=0;j<16;j++){
      int e = i*4096 + t + j*256;         // 0..65535
      int n = 2304 + (e >> 9), k = e & 511;
      float v = (n < 2352) ? wr[(size_t)k*48 + (n-2304)] : 0.f;
      wtq[(size_t)n*512 + k] = f2b(v);
    }
    return;
  }
  int k0 = by*64, n0 = bx*64, cr = t >> 6, cc = t & 63;
  #pragma unroll
  for (int i=0;i<16;i++){
    int r = cr + i*4;
    tile[r][cc] = f2b(W[(size_t)(k0+r)*N + n0 + cc]);
  }
  __syncthreads();
  #pragma unroll
  for (int i=0;i<16;i++){
    int nn = cr + i*4;
    WT[(size_t)(n0+nn)*K + k0 + cc] = tile[cc][nn];
  }
}

// ---------------- bf16 MFMA GEMM: C[M,N] = A[M,K] @ BT[N,K]^T ----------------
// act: 1 = silu (bf16 out Cb), 2 = multiply by bf16 aux (fp32 out Cf)
__global__ __launch_bounds__(256) void k_mfma_gemm(const unsigned short* __restrict__ A,
    const unsigned short* __restrict__ BT, float* __restrict__ Cf,
    unsigned short* __restrict__ Cb, const unsigned short* __restrict__ auxb,
    int M, int N, int K, int act)
{
  __shared__ unsigned short As[128*64];
  __shared__ unsigned short Bs[128*64];
  int tid = threadIdx.x;
  int w = tid >> 6, lane = tid & 63;
  int wm = (w >> 1)*64, wn = (w & 1)*64;
  int m16 = lane & 15, quad = lane >> 4;
  int bm = blockIdx.y*128, bn = blockIdx.x*128;

  f32x4 acc[4][4];
  #pragma unroll
  for (int i=0;i<4;i++)
    #pragma unroll
    for (int j=0;j<4;j++) acc[i][j] = (f32x4){0.f,0.f,0.f,0.f};

  for (int kk = 0; kk < K; kk += 64){
    #pragma unroll
    for (int i=0;i<4;i++){
      int g = (w*4 + i)*64 + lane;
      int m = g >> 3, c = (g & 7) ^ (m & 7);
      async16(A  + (size_t)(bm+m)*K + kk + c*8, As + (w*4+i)*512);
      async16(BT + (size_t)(bn+m)*K + kk + c*8, Bs + (w*4+i)*512);
    }
    __syncthreads();
    #pragma unroll
    for (int s=0;s<2;s++){
      short8 af[4], bf[4];
      #pragma unroll
      for (int mt=0;mt<4;mt++){
        int m = wm + mt*16 + m16;
        int idx = m*8 + ((s*4 + quad) ^ (m & 7));
        af[mt] = *(const short8*)(As + idx*8);
      }
      #pragma unroll
      for (int nt=0;nt<4;nt++){
        int n = wn + nt*16 + m16;
        int idx = n*8 + ((s*4 + quad) ^ (n & 7));
        bf[nt] = *(const short8*)(Bs + idx*8);
      }
      #pragma unroll
      for (int mt=0;mt<4;mt++)
        #pragma unroll
        for (int nt=0;nt<4;nt++)
          acc[mt][nt] = __builtin_amdgcn_mfma_f32_16x16x32_bf16(af[mt], bf[nt], acc[mt][nt], 0, 0, 0);
    }
    __syncthreads();
  }
  #pragma unroll
  for (int mt=0;mt<4;mt++){
    #pragma unroll
    for (int r=0;r<4;r++){
      int row = bm + wm + mt*16 + quad*4 + r;
      #pragma unroll
      for (int nt=0;nt<4;nt++){
        int col = bn + wn + nt*16 + m16;
        float v = acc[mt][nt][r];
        if (act == 1) v = v/(1.f + __expf(-v));
        else if (act == 2) v *= bf2f(auxb[(size_t)row*N + col]);
        if (Cf) Cf[(size_t)row*N + col] = v;
        if (Cb) Cb[(size_t)row*N + col] = f2b(v);
      }
    }
  }
}

// ---------------- fused GEMM: [qkv | params | gate] = latent @ BT (N=3200) ----------
// Epilogue does the whole k_feat: per-head rmsnorm + rope + elu+1 in registers.
__global__ __launch_bounds__(256) void k_gemm_fused(const unsigned short* __restrict__ A,
    const unsigned short* __restrict__ BT, const float* __restrict__ w_qn,
    const float* __restrict__ w_kn, unsigned short* __restrict__ qf,
    unsigned short* __restrict__ kf, unsigned short* __restrict__ vf,
    float* __restrict__ params, unsigned short* __restrict__ gateb)
{
  __shared__ unsigned short As[128*64];
  __shared__ unsigned short Bs[128*64];
  const int K = LATD, N = NFUSE;
  int tid = threadIdx.x;
  int w = tid >> 6, lane = tid & 63;
  int wm = (w >> 1)*64, wn = (w & 1)*64;
  int m16 = lane & 15, quad = lane >> 4;
  int bm = blockIdx.y*128, bn = blockIdx.x*128;

  f32x4 acc[4][4];
  #pragma unroll
  for (int i=0;i<4;i++)
    #pragma unroll
    for (int j=0;j<4;j++) acc[i][j] = (f32x4){0.f,0.f,0.f,0.f};

  for (int kk = 0; kk < K; kk += 64){
    #pragma unroll
    for (int i=0;i<4;i++){
      int g = (w*4 + i)*64 + lane;
      int m = g >> 3, c = (g & 7) ^ (m & 7);
      async16(A  + (size_t)(bm+m)*K + kk + c*8, As + (w*4+i)*512);
      async16(BT + (size_t)(bn+m)*K + kk + c*8, Bs + (w*4+i)*512);
    }
    __syncthreads();
    #pragma unroll
    for (int s=0;s<2;s++){
      short8 af[4], bf[4];
      #pragma unroll
      for (int mt=0;mt<4;mt++){
        int m = wm + mt*16 + m16;
        int idx = m*8 + ((s*4 + quad) ^ (m & 7));
        af[mt] = *(const short8*)(As + idx*8);
      }
      #pragma unroll
      for (int nt=0;nt<4;nt++){
        int n = wn + nt*16 + m16;
        int idx = n*8 + ((s*4 + quad) ^ (n & 7));
        bf[nt] = *(const short8*)(Bs + idx*8);
      }
      #pragma unroll
      for (int mt=0;mt<4;mt++)
        #pragma unroll
        for (int nt=0;nt<4;nt++)
          acc[mt][nt] = __builtin_amdgcn_mfma_f32_16x16x32_bf16(af[mt], bf[nt], acc[mt][nt], 0, 0, 0);
    }
    __syncthreads();
  }

  int colbase = bn + wn;                // 64-aligned; wave owns cols [colbase, colbase+64)
  if (colbase < 2304){
    int sec = colbase >= 1536 ? 2 : (colbase >= 768 ? 1 : 0);   // 0=q 1=k 2=v
    int h = (colbase - sec*768) >> 6;
    if (sec == 2){
      #pragma unroll
      for (int mt=0;mt<4;mt++)
        #pragma unroll
        for (int r=0;r<4;r++){
          int row = bm + wm + mt*16 + quad*4 + r;
          int b = row >> 10, t = row & 1023;
          size_t ob = (((size_t)(b*NHEAD+h))*SEQ + t)*64;
          #pragma unroll
          for (int nt=0;nt<4;nt++)
            vf[ob + nt*16 + m16] = f2b(acc[mt][nt][r]);
        }
    } else {
      const float* wnp = sec ? w_kn : w_qn;
      unsigned short* of = sec ? kf : qf;
      float wv4[4];
      #pragma unroll
      for (int nt=0;nt<4;nt++) wv4[nt] = wnp[nt*16 + m16];
      float inv0 = exp2f(-(float)m16*(1.f/32.f)*13.28771237954945f);  // 10000^{-m16/32}
      float inv1 = inv0 * 0.01f;                                      // * 10000^{-16/32}
      #pragma unroll
      for (int mt=0;mt<4;mt++)
        #pragma unroll
        for (int r=0;r<4;r++){
          int row = bm + wm + mt*16 + quad*4 + r;
          int b = row >> 10, t = row & 1023;
          float s = 0.f;
          #pragma unroll
          for (int nt=0;nt<4;nt++) s += acc[mt][nt][r]*acc[mt][nt][r];
          s += __shfl_xor(s, 1, 64); s += __shfl_xor(s, 2, 64);
          s += __shfl_xor(s, 4, 64); s += __shfl_xor(s, 8, 64);
          float rs = rsqrtf(s*(1.f/64.f) + 1e-6f);
          float qv[4];
          #pragma unroll
          for (int nt=0;nt<4;nt++) qv[nt] = acc[mt][nt][r]*rs*wv4[nt];
          float s0,c0,s1,c1;
          __sincosf((float)t*inv0, &s0, &c0);
          __sincosf((float)t*inv1, &s1, &c1);
          size_t ob = (((size_t)(b*NHEAD+h))*SEQ + t)*64;
          #pragma unroll
          for (int nt=0;nt<4;nt++){
            float rot = (nt < 2) ? -qv[nt+2] : qv[nt-2];
            float cs = (nt & 1) ? c1 : c0, sn = (nt & 1) ? s1 : s0;
            float val = qv[nt]*cs + rot*sn;
            val = (val > 0.f) ? val + 1.f : __expf(val);
            of[ob + nt*16 + m16] = f2b(val);
          }
        }
    }
  } else if (colbase < 2432){
    // resonance params, cols 2304..2351 valid
    #pragma unroll
    for (int mt=0;mt<4;mt++)
      #pragma unroll
      for (int r=0;r<4;r++){
        int row = bm + wm + mt*16 + quad*4 + r;
        #pragma unroll
        for (int nt=0;nt<4;nt++){
          int p = colbase + nt*16 + m16 - 2304;
          if (p < 48) params[(size_t)row*48 + p] = acc[mt][nt][r];
        }
      }
  } else {
    // out-gate: silu -> bf16
    #pragma unroll
    for (int mt=0;mt<4;mt++)
      #pragma unroll
      for (int r=0;r<4;r++){
        int row = bm + wm + mt*16 + quad*4 + r;
        #pragma unroll
        for (int nt=0;nt<4;nt++){
          int gc = colbase + nt*16 + m16 - 2432;
          float v = acc[mt][nt][r];
          v = v/(1.f + __expf(-v));
          gateb[(size_t)row*D_MODEL + gc] = f2b(v);
        }
      }
  }
}

// ---------------- coefficients from params: one thread per (row, head) ------------
__global__ __launch_bounds__(256) void k_coef(const float* __restrict__ params,
    const float* __restrict__ hdec, const float* __restrict__ temp,
    float* __restrict__ cKV, float* __restrict__ cG)
{
  int idx = blockIdx.x*256 + threadIdx.x;     // < 24576
  int row = idx / NHEAD, h = idx % NHEAD;
  int b = row >> 10, t = row & 1023;
  const float* pr = params + (size_t)row*48 + h*4;
  float sa = sigf(pr[0]);
  float sp = sigf(pr[1])*3.14159265358979323846f;
  float ca = sigf(pr[2]);
  float cp = sigf(pr[3])*3.14159265358979323846f;
  float z = sa*ca*cosf(sp - cp)*temp[0];
  float gate = fminf(fmaxf(sigf(z)*1.2f - 0.1f, 0.05f), 0.95f);
  float d = decay_of(hdec[h]);
  float df = expf((float)(t+1)*logf(d));
  float g = df/(df + 1e-8f);
  int ci = (b*NHEAD + h)*SEQ + t;
  cKV[ci] = g*gate*(1.f - d);
  cG[ci]  = 1.f/gate;
}

// ---------------- intra-chunk: MFMA scores + num/den + P^T/zP ----------------
__global__ __launch_bounds__(256) void k_intra(const unsigned short* __restrict__ qf,
    const unsigned short* __restrict__ kf, const unsigned short* __restrict__ vf,
    const float* __restrict__ cKVb, const float* __restrict__ cGb,
    const float* __restrict__ hdec, float* __restrict__ numb,
    float* __restrict__ denb, float* __restrict__ Pb, float* __restrict__ zPb)
{
  __shared__ __align__(16) unsigned short Qb[64*PQ];   // Q_f  [t][k]
  __shared__ __align__(16) unsigned short Kb[64*PQ];   // K_f  [s][d]
  __shared__ __align__(16) unsigned short KtS[64*PQ];  // (K_f*cps)^T [d][s]
  __shared__ __align__(16) unsigned short Wb[64*PQ];   // Wn   [t][s]
  __shared__ __align__(16) unsigned short Vt[80*PQ];   // V^T  [e][s]; row64 = invgate; 65..79 = 0
  __shared__ float cn[64], cps[64];
  int bid = blockIdx.x;
  int chunk = bid & 15, bh = bid >> 4, h = bh % NHEAD;
  int tid = threadIdx.x, w = tid >> 6, lane = tid & 63;
  int m16 = lane & 15, quad = lane >> 4;
  size_t base = ((size_t)bh*SEQ + chunk*64)*64;
  float d = decay_of(hdec[h]);
  float l2d = log2f(d);

  if (tid < 64){
    float c = cKVb[bh*SEQ + chunk*64 + tid];
    float pw = exp2f((float)(63 - tid)*l2d);
    cn[tid] = c;
    cps[tid] = c*pw;
    Vt[64*PQ + tid] = f2b(cGb[bh*SEQ + chunk*64 + tid]);
  }
  for (int i = tid; i < 15*PQ; i += 256) Vt[65*PQ + i] = 0;
  __syncthreads();   // cps ready for KtS staging

  #pragma unroll
  for (int i=0;i<2;i++){
    int g = tid + i*256;
    int r = g >> 3, c8 = (g & 7)*8;
    *(short8*)(Qb + r*PQ + c8) = *(const short8*)(qf + base + r*64 + c8);
    *(short8*)(Kb + r*PQ + c8) = *(const short8*)(kf + base + r*64 + c8);
  }
  {
    int s = tid & 63;
    float cpss = cps[s];
    #pragma unroll
    for (int i=0;i<2;i++){
      int c8 = ((tid >> 6) + i*4)*8;
      short8 vv = *(const short8*)(vf + base + s*64 + c8);
      short8 kk = *(const short8*)(kf + base + s*64 + c8);
      #pragma unroll
      for (int j=0;j<8;j++){
        Vt[(c8+j)*PQ + s] = ((unsigned short*)&vv)[j];
        KtS[(c8+j)*PQ + s] = f2b(bf2f(((unsigned short*)&kk)[j])*cpss);
      }
    }
  }
  __syncthreads();

  int trow = w*16 + quad*4;
  for (int stile=0; stile<4; stile++){
    if (stile > w){
      #pragma unroll
      for (int r=0;r<4;r++) Wb[(trow+r)*PQ + stile*16 + m16] = 0;
      continue;
    }
    f32x4 acc = (f32x4){0.f,0.f,0.f,0.f};
    #pragma unroll
    for (int ks=0;ks<2;ks++){
      short8 a = *(const short8*)(Qb + (w*16 + m16)*PQ + ks*32 + quad*8);
      short8 b = *(const short8*)(Kb + (stile*16 + m16)*PQ + ks*32 + quad*8);
      acc = __builtin_amdgcn_mfma_f32_16x16x32_bf16(a, b, acc, 0, 0, 0);
    }
    int s = stile*16 + m16;
    float cns = cn[s];
    #pragma unroll
    for (int r=0;r<4;r++){
      int t = trow + r;
      float wv = 0.f;
      if (s <= t) wv = acc[r]*exp2f((float)(t-s)*l2d)*cns;
      Wb[t*PQ + s] = f2b(wv);
    }
  }
  __syncthreads();

  {
    f32x4 acc[5];
    #pragma unroll
    for (int et=0;et<5;et++) acc[et] = (f32x4){0.f,0.f,0.f,0.f};
    #pragma unroll
    for (int et=0;et<5;et++)
      #pragma unroll
      for (int ks=0;ks<2;ks++){
        short8 a = *(const short8*)(Wb + (w*16 + m16)*PQ + ks*32 + quad*8);
        short8 b = *(const short8*)(Vt + (et*16 + m16)*PQ + ks*32 + quad*8);
        acc[et] = __builtin_amdgcn_mfma_f32_16x16x32_bf16(a, b, acc[et], 0, 0, 0);
      }
    #pragma unroll
    for (int et=0;et<4;et++)
      #pragma unroll
      for (int r=0;r<4;r++)
        numb[base + (size_t)(trow+r)*64 + et*16 + m16] = acc[et][r];
    if (m16 == 0){
      #pragma unroll
      for (int r=0;r<4;r++)
        denb[bh*SEQ + chunk*64 + trow + r] = acc[4][r];
    }
  }
  {
    #pragma unroll
    for (int j=0;j<5;j++){
      int tIdx = w + 4*j;
      int et = tIdx >> 2, dt = tIdx & 3;
      f32x4 acc = (f32x4){0.f,0.f,0.f,0.f};
      #pragma unroll
      for (int ks=0;ks<2;ks++){
        short8 a = *(const short8*)(Vt  + (et*16 + m16)*PQ + ks*32 + quad*8);
        short8 b = *(const short8*)(KtS + (dt*16 + m16)*PQ + ks*32 + quad*8);
        acc = __builtin_amdgcn_mfma_f32_16x16x32_bf16(a, b, acc, 0, 0, 0);
      }
      if (et < 4){
        #pragma unroll
        for (int r=0;r<4;r++)
          Pb[(size_t)bid*4096 + (et*16 + quad*4 + r)*64 + dt*16 + m16] = acc[r];
      } else {
        if (quad == 0) zPb[bid*64 + dt*16 + m16] = acc[0];
      }
    }
  }
}

// ---------------- chunk-level state scan -> bf16 Sprev/zprev ----------------
__global__ __launch_bounds__(256) void k_scan(const float* __restrict__ Pb,
    const float* __restrict__ zPb, unsigned short* __restrict__ Sprev,
    unsigned short* __restrict__ zprev, const float* __restrict__ hdec)
{
  int bh = blockIdx.x >> 2, part = blockIdx.x & 3;
  int h = bh % NHEAD, tid = threadIdx.x;
  float d = decay_of(hdec[h]);
  float d64 = exp2f(64.f*log2f(d));
  int idx = part*1024 + tid*4;
  float4 S = make_float4(0.f,0.f,0.f,0.f);
  for (int c=0;c<NCHUNK;c++){
    size_t off = ((size_t)bh*NCHUNK + c)*4096 + idx;
    unsigned int lo = (unsigned int)f2b(S.x) | ((unsigned int)f2b(S.y) << 16);
    unsigned int hi = (unsigned int)f2b(S.z) | ((unsigned int)f2b(S.w) << 16);
    *(uint2*)(Sprev + off) = make_uint2(lo, hi);
    float4 p = *(const float4*)(Pb + off);
    S.x = S.x*d64 + p.x; S.y = S.y*d64 + p.y;
    S.z = S.z*d64 + p.z; S.w = S.w*d64 + p.w;
  }
  if (part == 0 && tid < 64){
    float z = 0.f;
    for (int c=0;c<NCHUNK;c++){
      int zoff = (bh*NCHUNK + c)*64 + tid;
      zprev[zoff] = f2b(z);
      z = z*d64 + zPb[zoff];
    }
  }
}

// ---------------- cross-chunk combine via MFMA + final attention out ----------------
__global__ __launch_bounds__(256) void k_cross(const unsigned short* __restrict__ qf,
    const unsigned short* __restrict__ Sprev, const unsigned short* __restrict__ zprev,
    const float* __restrict__ numb, const float* __restrict__ denb,
    const float* __restrict__ hdec, float* __restrict__ attn)
{
  __shared__ __align__(16) unsigned short Qb[64*PQ];   // Q_f [t][k]
  __shared__ __align__(16) unsigned short Sp[80*PQ];   // S [e][d]; row64 = zprev; 65..79 = 0
  __shared__ float den_sm[64];
  int bid = blockIdx.x;
  int chunk = bid & 15, bh = bid >> 4, h = bh % NHEAD, b = bh / NHEAD;
  int tid = threadIdx.x, w = tid >> 6, lane = tid & 63;
  int m16 = lane & 15, quad = lane >> 4;
  size_t base = ((size_t)bh*SEQ + chunk*64)*64;
  float d = decay_of(hdec[h]);
  float l2d = log2f(d);

  #pragma unroll
  for (int i=0;i<2;i++){
    int g = tid + i*256;
    int r = g >> 3, c8 = (g & 7)*8;
    *(short8*)(Qb + r*PQ + c8) = *(const short8*)(qf + base + r*64 + c8);
    *(short8*)(Sp + r*PQ + c8) = *(const short8*)(Sprev + (size_t)bid*4096 + r*64 + c8);
  }
  if (tid < 64) Sp[64*PQ + tid] = zprev[bid*64 + tid];
  for (int i = tid; i < 15*PQ; i += 256) Sp[65*PQ + i] = 0;
  __syncthreads();

  f32x4 acc[5];
  #pragma unroll
  for (int et=0;et<5;et++) acc[et] = (f32x4){0.f,0.f,0.f,0.f};
  #pragma unroll
  for (int et=0;et<5;et++)
    #pragma unroll
    for (int ks=0;ks<2;ks++){
      short8 a = *(const short8*)(Qb + (w*16 + m16)*PQ + ks*32 + quad*8);
      short8 b = *(const short8*)(Sp + (et*16 + m16)*PQ + ks*32 + quad*8);
      acc[et] = __builtin_amdgcn_mfma_f32_16x16x32_bf16(a, b, acc[et], 0, 0, 0);
    }
  int trow = w*16 + quad*4;
  if (m16 == 0){
    #pragma unroll
    for (int r=0;r<4;r++){
      int tl = trow + r;
      float pw = exp2f((float)(tl+1)*l2d);
      float den = fmaxf(denb[bh*SEQ + chunk*64 + tl] + pw*acc[4][r], 1e-5f);
      den_sm[tl] = 1.f/den;
    }
  }
  __syncthreads();
  #pragma unroll
  for (int r=0;r<4;r++){
    int tl = trow + r;
    float pw = exp2f((float)(tl+1)*l2d);
    float invden = den_sm[tl];
    int tg = chunk*64 + tl;
    #pragma unroll
    for (int et=0;et<4;et++){
      int e = et*16 + m16;
      float nm = numb[base + (size_t)tl*64 + e] + pw*acc[et][r];
      attn[((size_t)(b*SEQ + tg))*D_MODEL + h*64 + e] = nm*invden;
    }
  }
}

extern "C" void kernel_launch(void* const* d_in, const int* in_sizes, int n_in,
                              void* d_out, int out_size, void* d_ws, size_t ws_size,
                              hipStream_t stream)
{
  (void)in_sizes; (void)n_in; (void)out_size; (void)ws_size;
  const float* x       = (const float*)d_in[0];
  const float* w_ln    = (const float*)d_in[1];
  const float* w_comp  = (const float*)d_in[2];
  const float* w_qkv   = (const float*)d_in[3];
  const float* w_reso  = (const float*)d_in[4];
  const float* w_qn    = (const float*)d_in[5];
  const float* w_kn    = (const float*)d_in[6];
  const float* hdec    = (const float*)d_in[7];
  const float* temp    = (const float*)d_in[8];
  const float* w_ogate = (const float*)d_in[9];
  const float* w_proj  = (const float*)d_in[10];
  const float* w_mn    = (const float*)d_in[11];
  float* ws = (float*)d_ws;
  float* out = (float*)d_out;

  // fp32 region (floats)
  const size_t o_params = 0;                                   // 2048*48
  const size_t o_cKV    = o_params + (size_t)NROWS*48;
  const size_t o_cG     = o_cKV    + (size_t)NBH*SEQ;
  const size_t o_den    = o_cG     + (size_t)NBH*SEQ;
  const size_t o_P      = o_den    + (size_t)NBH*SEQ;          // 24*16*4096 ([e][d])
  const size_t o_zP     = o_P      + (size_t)NBH*NCHUNK*4096;
  const size_t o_attn   = o_zP     + (size_t)NBH*NCHUNK*64;
  const size_t o_numb   = o_attn   + (size_t)NROWS*D_MODEL;
  const size_t o_end    = o_numb   + (size_t)NBH*SEQ*64;

  // bf16 region (ushorts)
  unsigned short* bws = (unsigned short*)(ws + o_end);
  const size_t u_xn     = 0;
  const size_t u_latent = u_xn     + (size_t)NROWS*D_MODEL;
  const size_t u_memn   = u_latent + (size_t)NROWS*LATD;
  const size_t u_q      = u_memn   + (size_t)NROWS*D_MODEL;
  const size_t u_k      = u_q      + (size_t)NBH*SEQ*64;
  const size_t u_v      = u_k      + (size_t)NBH*SEQ*64;
  const size_t u_gate   = u_v      + (size_t)NBH*SEQ*64;       // 2048*768
  const size_t u_S      = u_gate   + (size_t)NROWS*D_MODEL;    // bf16 Sprev
  const size_t u_zprev  = u_S      + (size_t)NBH*NCHUNK*4096;
  const size_t u_wtc    = u_zprev  + (size_t)NBH*NCHUNK*64;
  const size_t u_wtq    = u_wtc    + (size_t)LATD*D_MODEL;     // 2432*512, wtg follows
  const size_t u_wtg    = u_wtq    + (size_t)2432*LATD;        // contiguous: fused BT rows 2432..3199
  const size_t u_wtp    = u_wtg    + (size_t)D_MODEL*LATD;

  // 1. all weight converts (640 blocks, one launch)
  k_cvt_all<<<640, 256, 0, stream>>>(w_comp, w_qkv, w_reso, w_ogate, w_proj,
      bws + u_wtc, bws + u_wtq, bws + u_wtg, bws + u_wtp);
  // 2. xn = rmsnorm(x, w_ln) -> bf16
  k_rmsnorm_bf<<<NROWS, 256, 0, stream>>>(x, w_ln, bws + u_xn);
  // 3. latent = silu(xn @ w_compress) -> bf16
  k_mfma_gemm<<<dim3(LATD/128, NROWS/128), 256, 0, stream>>>(bws + u_xn, bws + u_wtc,
      nullptr, bws + u_latent, nullptr, NROWS, LATD, D_MODEL, 1);
  // 4. fused qkv+params+gate GEMM with feat epilogue (400 blocks)
  k_gemm_fused<<<dim3(NFUSE/128, NROWS/128), 256, 0, stream>>>(bws + u_latent, bws + u_wtq,
      w_qn, w_kn, bws + u_q, bws + u_k, bws + u_v, ws + o_params, bws + u_gate);
  // 5. coefficients
  k_coef<<<NROWS*NHEAD/256, 256, 0, stream>>>(ws + o_params, hdec, temp, ws + o_cKV, ws + o_cG);
  // 6. intra-chunk (MFMA)
  k_intra<<<NBH*NCHUNK, 256, 0, stream>>>(bws + u_q, bws + u_k, bws + u_v,
      ws + o_cKV, ws + o_cG, hdec, ws + o_numb, ws + o_den, ws + o_P, ws + o_zP);
  // 7. chunk-level scan -> bf16 states
  k_scan<<<NBH*4, 256, 0, stream>>>(ws + o_P, ws + o_zP, bws + u_S, bws + u_zprev, hdec);
  // 8. cross-chunk combine (MFMA) -> attn fp32
  k_cross<<<NBH*NCHUNK, 256, 0, stream>>>(bws + u_q, bws + u_S, bws + u_zprev,
      ws + o_numb, ws + o_den, hdec, ws + o_attn);
  // 9. memnorm -> bf16
  k_rmsnorm_bf<<<NROWS, 256, 0, stream>>>(ws + o_attn, w_mn, bws + u_memn);
  // 10. out = (memn @ w_proj) * gate
  k_mfma_gemm<<<dim3(D_MODEL/128, NROWS/128), 256, 0, stream>>>(bws + u_memn, bws + u_wtp,
      out, nullptr, bws + u_gate, NROWS, D_MODEL, D_MODEL, 2);
}